// Round 11
// baseline (393.945 us; speedup 1.0000x reference)
//
#include <hip/hip_runtime.h>
#include <math.h>

#define NB 16
#define NN 2048
#define NF 128
#define NH 128
#define NO 64

typedef short bf16x8 __attribute__((ext_vector_type(8)));
typedef float f32x4 __attribute__((ext_vector_type(4)));
typedef unsigned short u16;
typedef unsigned int u32;

#define LOG2E 1.4426950408889634f
#define EXPSHIFT 43.28085122666891f  // 30 * log2(e)

__device__ __forceinline__ u16 f2bf(float f) {
  u32 u = __builtin_bit_cast(u32, f);
  return (u16)((u + 0x7fffu + ((u >> 16) & 1u)) >> 16);
}
__device__ __forceinline__ float bf2f(u16 h) {
  u32 u = ((u32)h) << 16;
  return __builtin_bit_cast(float, u);
}

__device__ __forceinline__ void gload16(const void* g, void* l) {
  __builtin_amdgcn_global_load_lds((const __attribute__((address_space(1))) void*)g,
                                   (__attribute__((address_space(3))) void*)l, 16, 0, 0);
}
__device__ __forceinline__ f32x4 mfma16(bf16x8 a, bf16x8 b, f32x4 c) {
  return __builtin_amdgcn_mfma_f32_16x16x32_bf16(a, b, c, 0, 0, 0);
}
// exp(lrelu(z) - 30): max, mul, fma, v_exp
__device__ __forceinline__ float explr(float z) {
  return __builtin_amdgcn_exp2f(fmaf(fmaxf(z, 0.2f * z), LOG2E, -EXPSHIFT));
}

// ---------------- K_prep: Wg + adj swizzle + support GEMM, one launch --------
// bid 0        : Wg_sw = gat_w bf16 [kblk 16][col 64][8]
// bid 1..1024  : adj_sw = adj bf16 [ntile 32][ktile 32][kblk 8][row 64][8]
// bid 1025..1536: support: suppT_sw ktile (64 rows of x @ W), W self-cast
__global__ __launch_bounds__(256) void k_prep(const float* __restrict__ x,
                                              const float* __restrict__ adj,
                                              const float* __restrict__ gcn_w,
                                              const float* __restrict__ gat_w,
                                              u16* __restrict__ suppT_sw,
                                              u16* __restrict__ adj_sw,
                                              u16* __restrict__ Wg_sw) {
  __shared__ __align__(16) u16 ts[64 * 136];  // 17.4KB
  __shared__ __align__(16) u16 Bs[16384];     // 32KB W image; reused as os
  const int t = threadIdx.x;
  const int bid = blockIdx.x;
  if (bid == 0) {
#pragma unroll
    for (int it = 0; it < 4; ++it) {
      const int s = t + it * 256;  // [kb 16][col 64]
      const int kb = s >> 6, col = s & 63;
      u16 tmp[8];
#pragma unroll
      for (int j = 0; j < 8; ++j) tmp[j] = f2bf(gat_w[(kb * 8 + j) * 64 + col]);
      uint4 o;
      o.x = (u32)tmp[0] | ((u32)tmp[1] << 16);
      o.y = (u32)tmp[2] | ((u32)tmp[3] << 16);
      o.z = (u32)tmp[4] | ((u32)tmp[5] << 16);
      o.w = (u32)tmp[6] | ((u32)tmp[7] << 16);
      *(uint4*)&Wg_sw[(size_t)s * 8] = o;
    }
  } else if (bid < 1025) {
    const int tile = bid - 1;  // [nt 32][kt 32]
    const int n0 = (tile >> 5) * 64, m0 = (tile & 31) * 64;
#pragma unroll
    for (int k = 0; k < 4; ++k) {
      const int s = t + k * 256;  // 1024 float4 slots
      const int row = s >> 4, c4 = (s & 15) * 4;
      const float4 f = *(const float4*)&adj[(size_t)(n0 + row) * 2048 + m0 + c4];
      uint2 pk;
      pk.x = (u32)f2bf(f.x) | ((u32)f2bf(f.y) << 16);
      pk.y = (u32)f2bf(f.z) | ((u32)f2bf(f.w) << 16);
      *(uint2*)&ts[row * 136 + c4] = pk;
    }
    __syncthreads();
#pragma unroll
    for (int k = 0; k < 2; ++k) {
      const int s = t + k * 256;  // [kb 8][row 64]
      const int kb = s >> 6, row = s & 63;
      const uint4 v = *(const uint4*)&ts[row * 136 + kb * 8];
      *(uint4*)&adj_sw[(size_t)tile * 4096 + (size_t)s * 8] = v;
    }
  } else {
    const int sb = bid - 1025;  // 0..511, one 64-row ktile of supp
    const int m0g = sb * 64;
    const int w = t >> 6, l = t & 63;
    const int lg = l >> 4, lr = l & 15;
    // self-cast W image: Bs[kb 16][d 128][8] = gcn_w[kb*8+j][d]
#pragma unroll
    for (int i = 0; i < 8; ++i) {
      const int s = t + i * 256;
      const int kb = s >> 7, d = s & 127;
      u16 tmp[8];
#pragma unroll
      for (int j = 0; j < 8; ++j) tmp[j] = f2bf(gcn_w[(kb * 8 + j) * 128 + d]);
      uint4 o;
      o.x = (u32)tmp[0] | ((u32)tmp[1] << 16);
      o.y = (u32)tmp[2] | ((u32)tmp[3] << 16);
      o.z = (u32)tmp[4] | ((u32)tmp[5] << 16);
      o.w = (u32)tmp[6] | ((u32)tmp[7] << 16);
      *(uint4*)&Bs[(size_t)s * 8] = o;
    }
    // x tile 64x128 -> ts (row stride 136)
#pragma unroll
    for (int k = 0; k < 8; ++k) {
      const int s = t + k * 256;  // [row 64][c4 32]
      const int row = s >> 5, c4 = (s & 31) * 4;
      const float4 f = *(const float4*)&x[(size_t)(m0g + row) * 128 + c4];
      uint2 pk;
      pk.x = (u32)f2bf(f.x) | ((u32)f2bf(f.y) << 16);
      pk.y = (u32)f2bf(f.z) | ((u32)f2bf(f.w) << 16);
      *(uint2*)&ts[row * 136 + c4] = pk;
    }
    __syncthreads();
    f32x4 acc[8];
#pragma unroll
    for (int nf = 0; nf < 8; ++nf) {
      acc[nf][0] = 0.f; acc[nf][1] = 0.f;
      acc[nf][2] = 0.f; acc[nf][3] = 0.f;
    }
#pragma unroll
    for (int ks = 0; ks < 4; ++ks) {
      const int kb = ks * 4 + lg;
      const bf16x8 a = *(const bf16x8*)&ts[(w * 16 + lr) * 136 + kb * 8];
#pragma unroll
      for (int nf = 0; nf < 8; ++nf) {
        const bf16x8 bb = *(const bf16x8*)&Bs[((size_t)kb * 128 + nf * 16 + lr) * 8];
        acc[nf] = mfma16(a, bb, acc[nf]);
      }
    }
    __syncthreads();
    u16* os = Bs;  // transpose: os[d 128][m 64], stride 72 u16
#pragma unroll
    for (int nf = 0; nf < 8; ++nf) {
      const int d = nf * 16 + lr;
      const int mb = w * 16 + lg * 4;
      const u32 p0 = (u32)f2bf(acc[nf][0]) | ((u32)f2bf(acc[nf][1]) << 16);
      const u32 p1 = (u32)f2bf(acc[nf][2]) | ((u32)f2bf(acc[nf][3]) << 16);
      *(u32*)&os[d * 72 + mb] = p0;
      *(u32*)&os[d * 72 + mb + 2] = p1;
    }
    __syncthreads();
    const int b = m0g >> 11, mt = (m0g & 2047) >> 6;
#pragma unroll
    for (int i = 0; i < 4; ++i) {
      const int s = i * 256 + t;  // [kb 8][d 128]
      const int kb = s >> 7, d = s & 127;
      const uint4 v = *(const uint4*)&os[d * 72 + kb * 8];
      *(uint4*)&suppT_sw[((size_t)((b * 32 + mt) * 8 + kb)) * 1024 + (size_t)d * 8] = v;
    }
  }
}

// ---------------- K_gcn: 64x128 tile, BK=64, 8 waves + folded BN finalize ----
__global__ __launch_bounds__(512) void k_gcn(const u16* __restrict__ adj_sw,
                                             const u16* __restrict__ suppT_sw,
                                             const float* __restrict__ bias,
                                             const float* __restrict__ gamma,
                                             const float* __restrict__ beta,
                                             float* __restrict__ h,
                                             float* __restrict__ psum,
                                             float* __restrict__ psq,
                                             float* __restrict__ scale,
                                             float* __restrict__ shift,
                                             int* __restrict__ cnt) {
  const int flat = blockIdx.y * 32 + blockIdx.x;  // 0..511
  const int nf2 = (flat & 7) * 64 + (flat >> 3);  // XCD swizzle
  const int b = nf2 >> 5, nt = nf2 & 31;
  const int n0 = nt * 64;
  const int t = threadIdx.x;
  const int w = t >> 6, l = t & 63;
  const int wm = w >> 1, wn = w & 1;
  const int lg = l >> 4, lr = l & 15;
  __shared__ __align__(16) u16 As[2][4096];
  __shared__ __align__(16) u16 Bs[2][8192];
  __shared__ float redS[4][128], redQ[4][128];
  __shared__ int lastS;

  f32x4 acc[4];
#pragma unroll
  for (int nf = 0; nf < 4; ++nf) {
    acc[nf][0] = 0.f; acc[nf][1] = 0.f;
    acc[nf][2] = 0.f; acc[nf][3] = 0.f;
  }

#define GCN_STAGE(buf, kt)                                                        \
  {                                                                               \
    gload16(adj_sw + ((size_t)(nt * 32 + (kt))) * 4096 + (size_t)t * 8,           \
            &As[buf][t * 8]);                                                     \
    _Pragma("unroll") for (int i = 0; i < 2; ++i) {                               \
      const int s = i * 512 + t;                                                  \
      gload16(suppT_sw + ((size_t)(b * 32 + (kt))) * 8192 + (size_t)s * 8,        \
              &Bs[buf][s * 8]);                                                   \
    }                                                                             \
  }

  GCN_STAGE(0, 0);
  __syncthreads();
  for (int kt = 0; kt < 32; ++kt) {
    const int cur = kt & 1;
    if (kt + 1 < 32) GCN_STAGE(cur ^ 1, kt + 1);
#pragma unroll
    for (int kb = 0; kb < 2; ++kb) {
      const int ko = kb * 4 + lg;
      const bf16x8 a0 = *(const bf16x8*)&As[cur][(ko * 64 + wm * 16 + lr) * 8];
      const bf16x8 b0 = *(const bf16x8*)&Bs[cur][(ko * 128 + wn * 64 + lr) * 8];
      const bf16x8 b1 = *(const bf16x8*)&Bs[cur][(ko * 128 + wn * 64 + 16 + lr) * 8];
      const bf16x8 b2 = *(const bf16x8*)&Bs[cur][(ko * 128 + wn * 64 + 32 + lr) * 8];
      const bf16x8 b3 = *(const bf16x8*)&Bs[cur][(ko * 128 + wn * 64 + 48 + lr) * 8];
      acc[0] = mfma16(a0, b0, acc[0]);
      acc[1] = mfma16(a0, b1, acc[1]);
      acc[2] = mfma16(a0, b2, acc[2]);
      acc[3] = mfma16(a0, b3, acc[3]);
    }
    __syncthreads();
  }
#undef GCN_STAGE
#pragma unroll
  for (int nf = 0; nf < 4; ++nf) {
    const int d = wn * 64 + nf * 16 + lr;
    const float bv = bias[d];
    float s = 0.f, q = 0.f;
#pragma unroll
    for (int r = 0; r < 4; ++r) {
      const float v = acc[nf][r] + bv;
      const int row = n0 + wm * 16 + lg * 4 + r;
      h[((size_t)(b * NN + row)) * NH + d] = v;
      s += v;
      q = fmaf(v, v, q);
    }
    s += __shfl_xor(s, 16);
    s += __shfl_xor(s, 32);
    q += __shfl_xor(q, 16);
    q += __shfl_xor(q, 32);
    if (lg == 0) {
      redS[wm][d] = s;
      redQ[wm][d] = q;
    }
  }
  __syncthreads();
  if (t < 128) {
    const int blk = b * 32 + nt;
    psum[blk * 128 + t] = redS[0][t] + redS[1][t] + redS[2][t] + redS[3][t];
    psq[blk * 128 + t] = redQ[0][t] + redQ[1][t] + redQ[2][t] + redQ[3][t];
  }
  __threadfence();
  __syncthreads();
  if (t == 0) lastS = (atomicAdd(cnt, 1) == 511);
  __syncthreads();
  if (lastS) {
    __threadfence();
    const int d = t & 127, g = t >> 7;  // g 0..3
    float s = 0.f, q = 0.f;
    for (int i = g; i < 512; i += 4) {
      s += psum[i * 128 + d];
      q += psq[i * 128 + d];
    }
    redS[g][d] = s;
    redQ[g][d] = q;
    __syncthreads();
    if (t < 128) {
      s = redS[0][t] + redS[1][t] + redS[2][t] + redS[3][t];
      q = redQ[0][t] + redQ[1][t] + redQ[2][t] + redQ[3][t];
      const float inv = 1.f / (float)(NB * NN);
      const float mean = s * inv;
      const float var = q * inv - mean * mean;
      const float sc = gamma[t] * rsqrtf(var + 1e-5f);
      scale[t] = sc;
      shift[t] = beta[t] - mean * sc;
    }
  }
}

// ---------------- K_hp: MFMA version -----------------------------------------
__global__ __launch_bounds__(256) void k_hp(const float* __restrict__ h,
                                            const float* __restrict__ scale,
                                            const float* __restrict__ shift,
                                            const u16* __restrict__ Wg_sw,
                                            u16* __restrict__ hp_sw) {
  const int row0 = blockIdx.x * 64;
  const int t = threadIdx.x, w = t >> 6, l = t & 63;
  const int lg = l >> 4, lr = l & 15;
  __shared__ __align__(16) u16 him[8192];
  __shared__ __align__(16) u16 Wg[8192];
  __shared__ __align__(16) u16 hos[64][72];
  __shared__ float scs[128], shs[128];
#pragma unroll
  for (int i = 0; i < 4; ++i) {
    const int s0 = i * 256 + w * 64;
    gload16(Wg_sw + (size_t)(s0 + l) * 8, &Wg[(size_t)s0 * 8]);
  }
  if (t < 128) {
    scs[t] = scale[t];
    shs[t] = shift[t];
  }
  __syncthreads();
#pragma unroll
  for (int k = 0; k < 4; ++k) {
    const int s = t + k * 256;  // [row 64][kb 16]
    const int row = s >> 4, kb = s & 15;
    const float4 v0 = *(const float4*)&h[(size_t)(row0 + row) * NH + kb * 8];
    const float4 v1 = *(const float4*)&h[(size_t)(row0 + row) * NH + kb * 8 + 4];
    u16 p[8];
    p[0] = f2bf(fmaxf(fmaf(v0.x, scs[kb * 8 + 0], shs[kb * 8 + 0]), 0.f));
    p[1] = f2bf(fmaxf(fmaf(v0.y, scs[kb * 8 + 1], shs[kb * 8 + 1]), 0.f));
    p[2] = f2bf(fmaxf(fmaf(v0.z, scs[kb * 8 + 2], shs[kb * 8 + 2]), 0.f));
    p[3] = f2bf(fmaxf(fmaf(v0.w, scs[kb * 8 + 3], shs[kb * 8 + 3]), 0.f));
    p[4] = f2bf(fmaxf(fmaf(v1.x, scs[kb * 8 + 4], shs[kb * 8 + 4]), 0.f));
    p[5] = f2bf(fmaxf(fmaf(v1.y, scs[kb * 8 + 5], shs[kb * 8 + 5]), 0.f));
    p[6] = f2bf(fmaxf(fmaf(v1.z, scs[kb * 8 + 6], shs[kb * 8 + 6]), 0.f));
    p[7] = f2bf(fmaxf(fmaf(v1.w, scs[kb * 8 + 7], shs[kb * 8 + 7]), 0.f));
    uint4 o;
    o.x = (u32)p[0] | ((u32)p[1] << 16);
    o.y = (u32)p[2] | ((u32)p[3] << 16);
    o.z = (u32)p[4] | ((u32)p[5] << 16);
    o.w = (u32)p[6] | ((u32)p[7] << 16);
    const int boff = (row * 256 + kb * 16) ^ ((row & 7) << 4);
    *(uint4*)&him[boff >> 1] = o;
  }
  __syncthreads();
  f32x4 acc[4];
#pragma unroll
  for (int nf = 0; nf < 4; ++nf) {
    acc[nf][0] = 0.f; acc[nf][1] = 0.f;
    acc[nf][2] = 0.f; acc[nf][3] = 0.f;
  }
#pragma unroll
  for (int kks = 0; kks < 4; ++kks) {
    const int ko = kks * 4 + lg;
    const int arow = w * 16 + lr;
    const int aoff = (arow * 256 + ko * 16) ^ ((arow & 7) << 4);
    const bf16x8 a = *(const bf16x8*)&him[aoff >> 1];
#pragma unroll
    for (int nf = 0; nf < 4; ++nf) {
      const bf16x8 bfr = *(const bf16x8*)&Wg[(ko * 64 + nf * 16 + lr) * 8];
      acc[nf] = mfma16(a, bfr, acc[nf]);
    }
  }
#pragma unroll
  for (int nf = 0; nf < 4; ++nf) {
    const int col = nf * 16 + lr;
#pragma unroll
    for (int r = 0; r < 4; ++r) {
      hos[w * 16 + lg * 4 + r][col] = f2bf(acc[nf][r]);
    }
  }
  __syncthreads();
  const size_t tbase = (size_t)blockIdx.x * 4096;
#pragma unroll
  for (int k = 0; k < 2; ++k) {
    const int s = t + k * 256;
    const int kb = s >> 6, r6 = s & 63;
    const uint2 lo = *(const uint2*)&hos[r6][kb * 8];
    const uint2 hi = *(const uint2*)&hos[r6][kb * 8 + 4];
    uint4 o;
    o.x = lo.x; o.y = lo.y; o.z = hi.x; o.w = hi.y;
    *(uint4*)&hp_sw[tbase + kb * 512 + r6 * 8] = o;
  }
}

// ---------------- attn XCD swizzle helper ------------------------------------
__device__ __forceinline__ void attn_swz(int& b, int& nt, int& qtr) {
  const int flat = blockIdx.y * 512 + blockIdx.x;  // 0..2047
  const int lf = (flat & 7) * 256 + (flat >> 3);
  b = lf >> 7;
  const int rem = lf & 127;
  qtr = rem >> 5;
  nt = rem & 31;
}

// ---------------- K_attnA: partial D over m-quarter --------------------------
__global__ __launch_bounds__(256) void k_attnA(const u16* __restrict__ hp_sw,
                                               float* __restrict__ Dpart) {
  int b, nt, qtr;
  attn_swz(b, nt, qtr);
  const int t = threadIdx.x, w = t >> 6, l = t & 63;
  const int lg = l >> 4, lr = l & 15;
  __shared__ __align__(16) u16 Cs[2][4096];
  const u16* rbase = hp_sw + (size_t)(b * 32 + nt) * 4096;
  const int qrow = (w << 4) + lr;
  const bf16x8 bq0 = *(const bf16x8*)&rbase[(lg * 64 + qrow) * 8];
  const bf16x8 bq1 = *(const bf16x8*)&rbase[((lg + 4) * 64 + qrow) * 8];
  const u16* cb = hp_sw + (size_t)(b * 32 + qtr * 8) * 4096;
#pragma unroll
  for (int i = 0; i < 2; ++i) gload16(cb + (size_t)(i * 256 + t) * 8, &Cs[0][(i * 256 + t) * 8]);
  __syncthreads();
  float S = 0.f;
  for (int mt = 0; mt < 8; ++mt) {
    const int cur = mt & 1;
    if (mt + 1 < 8) {
#pragma unroll
      for (int i = 0; i < 2; ++i)
        gload16(cb + (size_t)(mt + 1) * 4096 + (size_t)(i * 256 + t) * 8,
                &Cs[cur ^ 1][(i * 256 + t) * 8]);
    }
#pragma unroll
    for (int mf = 0; mf < 4; ++mf) {
      const bf16x8 a0 = *(const bf16x8*)&Cs[cur][(lg * 64 + mf * 16 + lr) * 8];
      const bf16x8 a1 = *(const bf16x8*)&Cs[cur][((lg + 4) * 64 + mf * 16 + lr) * 8];
      f32x4 z;
      z[0] = 0.f; z[1] = 0.f; z[2] = 0.f; z[3] = 0.f;
      z = mfma16(a0, bq0, z);
      z = mfma16(a1, bq1, z);
      S += explr(z[0]) + explr(z[1]) + explr(z[2]) + explr(z[3]);
    }
    __syncthreads();
  }
  S += __shfl_xor(S, 16);
  S += __shfl_xor(S, 32);
  if (l < 16) Dpart[qtr * 32768 + b * NN + nt * 64 + qrow] = S;
}

// ---------------- K_attnB: partial S + folded final scale/out ----------------
__global__ __launch_bounds__(256) void k_attnB(const u16* __restrict__ hp_sw,
                                               const float* __restrict__ Dpart,
                                               float* __restrict__ Spart,
                                               int* __restrict__ cnt2,
                                               float* __restrict__ out) {
  int b, nt, qtr;
  attn_swz(b, nt, qtr);
  const int t = threadIdx.x, w = t >> 6, l = t & 63;
  const int lg = l >> 4, lr = l & 15;
  __shared__ __align__(16) u16 Cs[2][4096];
  __shared__ float iDs[512];
  __shared__ float Sv[64];
  __shared__ int lastQ;
  const u16* rbase = hp_sw + (size_t)(b * 32 + nt) * 4096;
  const int qrow = (w << 4) + lr;
  const bf16x8 bq0 = *(const bf16x8*)&rbase[(lg * 64 + qrow) * 8];
  const bf16x8 bq1 = *(const bf16x8*)&rbase[((lg + 4) * 64 + qrow) * 8];
  const u16* cb = hp_sw + (size_t)(b * 32 + qtr * 8) * 4096;
#pragma unroll
  for (int i = 0; i < 2; ++i) gload16(cb + (size_t)(i * 256 + t) * 8, &Cs[0][(i * 256 + t) * 8]);
#pragma unroll
  for (int i = 0; i < 2; ++i) {
    const int idx = t + i * 256;
    const int n = b * NN + qtr * 512 + idx;
    iDs[idx] = 1.f / (Dpart[n] + Dpart[32768 + n] + Dpart[65536 + n] + Dpart[98304 + n]);
  }
  __syncthreads();
  float S = 0.f;
  for (int mt = 0; mt < 8; ++mt) {
    const int cur = mt & 1;
    if (mt + 1 < 8) {
#pragma unroll
      for (int i = 0; i < 2; ++i)
        gload16(cb + (size_t)(mt + 1) * 4096 + (size_t)(i * 256 + t) * 8,
                &Cs[cur ^ 1][(i * 256 + t) * 8]);
    }
#pragma unroll
    for (int mf = 0; mf < 4; ++mf) {
      const bf16x8 a0 = *(const bf16x8*)&Cs[cur][(lg * 64 + mf * 16 + lr) * 8];
      const bf16x8 a1 = *(const bf16x8*)&Cs[cur][((lg + 4) * 64 + mf * 16 + lr) * 8];
      f32x4 z;
      z[0] = 0.f; z[1] = 0.f; z[2] = 0.f; z[3] = 0.f;
      z = mfma16(a0, bq0, z);
      z = mfma16(a1, bq1, z);
      const float4 dv = *(const float4*)&iDs[mt * 64 + mf * 16 + lg * 4];
      S = fmaf(explr(z[0]), dv.x, S);
      S = fmaf(explr(z[1]), dv.y, S);
      S = fmaf(explr(z[2]), dv.z, S);
      S = fmaf(explr(z[3]), dv.w, S);
    }
    __syncthreads();
  }
  S += __shfl_xor(S, 16);
  S += __shfl_xor(S, 32);
  if (l < 16) Spart[qtr * 32768 + b * NN + nt * 64 + qrow] = S;
  __threadfence();
  __syncthreads();
  if (t == 0) lastQ = (atomicAdd(&cnt2[b * 32 + nt], 1) == 3);
  __syncthreads();
  if (lastQ) {
    __threadfence();
    if (t < 64) {
      const int n = b * NN + nt * 64 + t;
      Sv[t] = Spart[n] + Spart[32768 + n] + Spart[65536 + n] + Spart[98304 + n];
    }
    __syncthreads();
    const int row = t >> 2;
    const float sc = Sv[row];
    const size_t R = (size_t)b * NN + nt * 64 + row;
#pragma unroll
    for (int hh = 0; hh < 2; ++hh) {
      const int kb = (t & 3) * 2 + hh;
      const u16* src = &rbase[(kb * 64 + row) * 8];
      float4 o0, o1;
      o0.x = bf2f(src[0]) * sc;
      o0.y = bf2f(src[1]) * sc;
      o0.z = bf2f(src[2]) * sc;
      o0.w = bf2f(src[3]) * sc;
      o1.x = bf2f(src[4]) * sc;
      o1.y = bf2f(src[5]) * sc;
      o1.z = bf2f(src[6]) * sc;
      o1.w = bf2f(src[7]) * sc;
      *(float4*)&out[R * NO + kb * 8] = o0;
      *(float4*)&out[R * NO + kb * 8 + 4] = o1;
    }
  }
}

extern "C" void kernel_launch(void* const* d_in, const int* in_sizes, int n_in,
                              void* d_out, int out_size, void* d_ws, size_t ws_size,
                              hipStream_t stream) {
  const float* x = (const float*)d_in[0];
  // d_in[1] = adj (unused)
  const float* adj_gcn = (const float*)d_in[2];
  const float* gcn_w = (const float*)d_in[3];
  const float* gcn_b = (const float*)d_in[4];
  const float* gamma = (const float*)d_in[5];
  const float* beta = (const float*)d_in[6];
  const float* gat_w = (const float*)d_in[7];
  float* out = (float*)d_out;
  float* ws = (float*)d_ws;

  // workspace layout (float units):
  u16* adj_sw = (u16*)ws;                  // [0, 2M)
  u16* suppT_sw = (u16*)(ws + 2097152);    // [2M, 4M)
  float* hbuf = ws + 4194304;              // [4M, 8M)
  u16* hp_sw = (u16*)(ws + 8388608);       // [8M, 9M)
  float* psum = ws + 9437184;              // 65536
  float* psq = psum + 65536;               // 65536
  float* scale = psq + 65536;              // 128
  float* shift = scale + 128;              // 128
  u16* Wg_sw = (u16*)(shift + 128);        // 8192 u16 (4096 f)
  float* Dpart = ws + 9617664;             // 131072
  float* Spart = Dpart + 131072;           // 131072
  int* cnt = (int*)(Spart + 131072);       // 1 + 512 ints
  int* cnt2 = cnt + 1;

  hipMemsetAsync((void*)cnt, 0, 513 * sizeof(int), stream);
  k_prep<<<dim3(1537), dim3(256), 0, stream>>>(x, adj_gcn, gcn_w, gat_w, suppT_sw, adj_sw, Wg_sw);
  k_gcn<<<dim3(32, 16), dim3(512), 0, stream>>>(adj_sw, suppT_sw, gcn_b, gamma, beta, hbuf,
                                                psum, psq, scale, shift, cnt);
  k_hp<<<dim3(512), dim3(256), 0, stream>>>(hbuf, scale, shift, Wg_sw, hp_sw);
  k_attnA<<<dim3(512, 4), dim3(256), 0, stream>>>(hp_sw, Dpart);
  k_attnB<<<dim3(512, 4), dim3(256), 0, stream>>>(hp_sw, Dpart, Spart, cnt2, out);
}

// Round 12
// 111.217 us; speedup vs baseline: 3.5421x; 3.5421x over previous
//
#include <hip/hip_runtime.h>
#include <math.h>

#define NB 16
#define NN 2048
#define NF 128
#define NH 128
#define NO 64

typedef short bf16x8 __attribute__((ext_vector_type(8)));
typedef float f32x4 __attribute__((ext_vector_type(4)));
typedef unsigned short u16;
typedef unsigned int u32;

#define LOG2E 1.4426950408889634f
#define EXPSHIFT 43.28085122666891f  // 30 * log2(e)

__device__ __forceinline__ u16 f2bf(float f) {
  u32 u = __builtin_bit_cast(u32, f);
  return (u16)((u + 0x7fffu + ((u >> 16) & 1u)) >> 16);
}
__device__ __forceinline__ float bf2f(u16 h) {
  u32 u = ((u32)h) << 16;
  return __builtin_bit_cast(float, u);
}

__device__ __forceinline__ void gload16(const void* g, void* l) {
  __builtin_amdgcn_global_load_lds((const __attribute__((address_space(1))) void*)g,
                                   (__attribute__((address_space(3))) void*)l, 16, 0, 0);
}
__device__ __forceinline__ f32x4 mfma16(bf16x8 a, bf16x8 b, f32x4 c) {
  return __builtin_amdgcn_mfma_f32_16x16x32_bf16(a, b, c, 0, 0, 0);
}
// exp(lrelu(z) - 30): max, mul, fma, v_exp
__device__ __forceinline__ float explr(float z) {
  return __builtin_amdgcn_exp2f(fmaf(fmaxf(z, 0.2f * z), LOG2E, -EXPSHIFT));
}

// ---------------- K_prep: Wg + adj swizzle + support GEMM, one launch --------
// bid 0        : Wg_sw = gat_w bf16 [kblk 16][col 64][8]
// bid 1..1024  : adj_sw = adj bf16 [ntile 32][ktile 32][kblk 8][row 64][8]
// bid 1025..1536: support: one 64-row ktile of (x @ W)^T, W self-cast from L2
__global__ __launch_bounds__(256) void k_prep(const float* __restrict__ x,
                                              const float* __restrict__ adj,
                                              const float* __restrict__ gcn_w,
                                              const float* __restrict__ gat_w,
                                              u16* __restrict__ suppT_sw,
                                              u16* __restrict__ adj_sw,
                                              u16* __restrict__ Wg_sw) {
  __shared__ __align__(16) u16 ts[64 * 136];  // 17.4KB
  __shared__ __align__(16) u16 Bs[16384];     // 32KB W image; reused as os
  const int t = threadIdx.x;
  const int bid = blockIdx.x;
  if (bid == 0) {
#pragma unroll
    for (int it = 0; it < 4; ++it) {
      const int s = t + it * 256;  // [kb 16][col 64]
      const int kb = s >> 6, col = s & 63;
      u16 tmp[8];
#pragma unroll
      for (int j = 0; j < 8; ++j) tmp[j] = f2bf(gat_w[(kb * 8 + j) * 64 + col]);
      uint4 o;
      o.x = (u32)tmp[0] | ((u32)tmp[1] << 16);
      o.y = (u32)tmp[2] | ((u32)tmp[3] << 16);
      o.z = (u32)tmp[4] | ((u32)tmp[5] << 16);
      o.w = (u32)tmp[6] | ((u32)tmp[7] << 16);
      *(uint4*)&Wg_sw[(size_t)s * 8] = o;
    }
  } else if (bid < 1025) {
    const int tile = bid - 1;  // [nt 32][kt 32]
    const int n0 = (tile >> 5) * 64, m0 = (tile & 31) * 64;
#pragma unroll
    for (int k = 0; k < 4; ++k) {
      const int s = t + k * 256;  // 1024 float4 slots
      const int row = s >> 4, c4 = (s & 15) * 4;
      const float4 f = *(const float4*)&adj[(size_t)(n0 + row) * 2048 + m0 + c4];
      uint2 pk;
      pk.x = (u32)f2bf(f.x) | ((u32)f2bf(f.y) << 16);
      pk.y = (u32)f2bf(f.z) | ((u32)f2bf(f.w) << 16);
      *(uint2*)&ts[row * 136 + c4] = pk;
    }
    __syncthreads();
#pragma unroll
    for (int k = 0; k < 2; ++k) {
      const int s = t + k * 256;  // [kb 8][row 64]
      const int kb = s >> 6, row = s & 63;
      const uint4 v = *(const uint4*)&ts[row * 136 + kb * 8];
      *(uint4*)&adj_sw[(size_t)tile * 4096 + (size_t)s * 8] = v;
    }
  } else {
    const int sb = bid - 1025;  // 0..511
    const int m0g = sb * 64;
    const int w = t >> 6, l = t & 63;
    const int lg = l >> 4, lr = l & 15;
    // self-cast W image: Bs[kb 16][d 128][8] = gcn_w[kb*8+j][d]
#pragma unroll
    for (int i = 0; i < 8; ++i) {
      const int s = t + i * 256;
      const int kb = s >> 7, d = s & 127;
      u16 tmp[8];
#pragma unroll
      for (int j = 0; j < 8; ++j) tmp[j] = f2bf(gcn_w[(kb * 8 + j) * 128 + d]);
      uint4 o;
      o.x = (u32)tmp[0] | ((u32)tmp[1] << 16);
      o.y = (u32)tmp[2] | ((u32)tmp[3] << 16);
      o.z = (u32)tmp[4] | ((u32)tmp[5] << 16);
      o.w = (u32)tmp[6] | ((u32)tmp[7] << 16);
      *(uint4*)&Bs[(size_t)s * 8] = o;
    }
    // x tile 64x128 -> ts (row stride 136)
#pragma unroll
    for (int k = 0; k < 8; ++k) {
      const int s = t + k * 256;  // [row 64][c4 32]
      const int row = s >> 5, c4 = (s & 31) * 4;
      const float4 f = *(const float4*)&x[(size_t)(m0g + row) * 128 + c4];
      uint2 pk;
      pk.x = (u32)f2bf(f.x) | ((u32)f2bf(f.y) << 16);
      pk.y = (u32)f2bf(f.z) | ((u32)f2bf(f.w) << 16);
      *(uint2*)&ts[row * 136 + c4] = pk;
    }
    __syncthreads();
    f32x4 acc[8];
#pragma unroll
    for (int nf = 0; nf < 8; ++nf) {
      acc[nf][0] = 0.f; acc[nf][1] = 0.f;
      acc[nf][2] = 0.f; acc[nf][3] = 0.f;
    }
#pragma unroll
    for (int ks = 0; ks < 4; ++ks) {
      const int kb = ks * 4 + lg;
      const bf16x8 a = *(const bf16x8*)&ts[(w * 16 + lr) * 136 + kb * 8];
#pragma unroll
      for (int nf = 0; nf < 8; ++nf) {
        const bf16x8 bb = *(const bf16x8*)&Bs[((size_t)kb * 128 + nf * 16 + lr) * 8];
        acc[nf] = mfma16(a, bb, acc[nf]);
      }
    }
    __syncthreads();
    u16* os = Bs;  // transpose: os[d 128][m 64], stride 72 u16
#pragma unroll
    for (int nf = 0; nf < 8; ++nf) {
      const int d = nf * 16 + lr;
      const int mb = w * 16 + lg * 4;
      const u32 p0 = (u32)f2bf(acc[nf][0]) | ((u32)f2bf(acc[nf][1]) << 16);
      const u32 p1 = (u32)f2bf(acc[nf][2]) | ((u32)f2bf(acc[nf][3]) << 16);
      *(u32*)&os[d * 72 + mb] = p0;
      *(u32*)&os[d * 72 + mb + 2] = p1;
    }
    __syncthreads();
    const int b = m0g >> 11, mt = (m0g & 2047) >> 6;
#pragma unroll
    for (int i = 0; i < 4; ++i) {
      const int s = i * 256 + t;  // [kb 8][d 128]
      const int kb = s >> 7, d = s & 127;
      const uint4 v = *(const uint4*)&os[d * 72 + kb * 8];
      *(uint4*)&suppT_sw[((size_t)((b * 32 + mt) * 8 + kb)) * 1024 + (size_t)d * 8] = v;
    }
  }
}

// ---------------- K_gcn: 64x128 tile, BK=64, 8 waves, XCD-swizzled -----------
__global__ __launch_bounds__(512) void k_gcn(const u16* __restrict__ adj_sw,
                                             const u16* __restrict__ suppT_sw,
                                             const float* __restrict__ bias,
                                             float* __restrict__ h,
                                             float* __restrict__ psum,
                                             float* __restrict__ psq) {
  const int flat = blockIdx.y * 32 + blockIdx.x;  // 0..511
  const int nf2 = (flat & 7) * 64 + (flat >> 3);  // XCD swizzle
  const int b = nf2 >> 5, nt = nf2 & 31;
  const int n0 = nt * 64;
  const int t = threadIdx.x;
  const int w = t >> 6, l = t & 63;
  const int wm = w >> 1, wn = w & 1;
  const int lg = l >> 4, lr = l & 15;
  __shared__ __align__(16) u16 As[2][4096];
  __shared__ __align__(16) u16 Bs[2][8192];
  __shared__ float redS[4][128], redQ[4][128];

  f32x4 acc[4];
#pragma unroll
  for (int nf = 0; nf < 4; ++nf) {
    acc[nf][0] = 0.f; acc[nf][1] = 0.f;
    acc[nf][2] = 0.f; acc[nf][3] = 0.f;
  }

#define GCN_STAGE(buf, kt)                                                        \
  {                                                                               \
    gload16(adj_sw + ((size_t)(nt * 32 + (kt))) * 4096 + (size_t)t * 8,           \
            &As[buf][t * 8]);                                                     \
    _Pragma("unroll") for (int i = 0; i < 2; ++i) {                               \
      const int s = i * 512 + t;                                                  \
      gload16(suppT_sw + ((size_t)(b * 32 + (kt))) * 8192 + (size_t)s * 8,        \
              &Bs[buf][s * 8]);                                                   \
    }                                                                             \
  }

  GCN_STAGE(0, 0);
  __syncthreads();
  for (int kt = 0; kt < 32; ++kt) {
    const int cur = kt & 1;
    if (kt + 1 < 32) GCN_STAGE(cur ^ 1, kt + 1);
#pragma unroll
    for (int kb = 0; kb < 2; ++kb) {
      const int ko = kb * 4 + lg;
      const bf16x8 a0 = *(const bf16x8*)&As[cur][(ko * 64 + wm * 16 + lr) * 8];
      const bf16x8 b0 = *(const bf16x8*)&Bs[cur][(ko * 128 + wn * 64 + lr) * 8];
      const bf16x8 b1 = *(const bf16x8*)&Bs[cur][(ko * 128 + wn * 64 + 16 + lr) * 8];
      const bf16x8 b2 = *(const bf16x8*)&Bs[cur][(ko * 128 + wn * 64 + 32 + lr) * 8];
      const bf16x8 b3 = *(const bf16x8*)&Bs[cur][(ko * 128 + wn * 64 + 48 + lr) * 8];
      acc[0] = mfma16(a0, b0, acc[0]);
      acc[1] = mfma16(a0, b1, acc[1]);
      acc[2] = mfma16(a0, b2, acc[2]);
      acc[3] = mfma16(a0, b3, acc[3]);
    }
    __syncthreads();
  }
#undef GCN_STAGE
#pragma unroll
  for (int nf = 0; nf < 4; ++nf) {
    const int d = wn * 64 + nf * 16 + lr;
    const float bv = bias[d];
    float s = 0.f, q = 0.f;
#pragma unroll
    for (int r = 0; r < 4; ++r) {
      const float v = acc[nf][r] + bv;
      const int row = n0 + wm * 16 + lg * 4 + r;
      h[((size_t)(b * NN + row)) * NH + d] = v;
      s += v;
      q = fmaf(v, v, q);
    }
    s += __shfl_xor(s, 16);
    s += __shfl_xor(s, 32);
    q += __shfl_xor(q, 16);
    q += __shfl_xor(q, 32);
    if (lg == 0) {
      redS[wm][d] = s;
      redQ[wm][d] = q;
    }
  }
  __syncthreads();
  if (t < 128) {
    const int blk = b * 32 + nt;
    psum[blk * 128 + t] = redS[0][t] + redS[1][t] + redS[2][t] + redS[3][t];
    psq[blk * 128 + t] = redQ[0][t] + redQ[1][t] + redQ[2][t] + redQ[3][t];
  }
}

// ---------------- BN finalize ------------------------------------------------
__global__ __launch_bounds__(1024) void k_bnstat2(const float* __restrict__ psum,
                                                  const float* __restrict__ psq,
                                                  const float* __restrict__ gamma,
                                                  const float* __restrict__ beta,
                                                  float* __restrict__ scale,
                                                  float* __restrict__ shift) {
  const int t = threadIdx.x;
  const int d = t & 127;
  const int g = t >> 7;
  float s = 0.f, q = 0.f;
  for (int i = g; i < 512; i += 8) {
    s += psum[i * 128 + d];
    q += psq[i * 128 + d];
  }
  __shared__ float ls[8][128], lq[8][128];
  ls[g][d] = s;
  lq[g][d] = q;
  __syncthreads();
  if (t < 128) {
    s = 0.f;
    q = 0.f;
#pragma unroll
    for (int i = 0; i < 8; ++i) {
      s += ls[i][t];
      q += lq[i][t];
    }
    const float inv = 1.f / (float)(NB * NN);
    const float mean = s * inv;
    const float var = q * inv - mean * mean;
    const float sc = gamma[t] * rsqrtf(var + 1e-5f);
    scale[t] = sc;
    shift[t] = beta[t] - mean * sc;
  }
}

// ---------------- K_hp: MFMA version -----------------------------------------
__global__ __launch_bounds__(256) void k_hp(const float* __restrict__ h,
                                            const float* __restrict__ scale,
                                            const float* __restrict__ shift,
                                            const u16* __restrict__ Wg_sw,
                                            u16* __restrict__ hp_sw) {
  const int row0 = blockIdx.x * 64;
  const int t = threadIdx.x, w = t >> 6, l = t & 63;
  const int lg = l >> 4, lr = l & 15;
  __shared__ __align__(16) u16 him[8192];
  __shared__ __align__(16) u16 Wg[8192];
  __shared__ __align__(16) u16 hos[64][72];
  __shared__ float scs[128], shs[128];
#pragma unroll
  for (int i = 0; i < 4; ++i) {
    const int s0 = i * 256 + w * 64;
    gload16(Wg_sw + (size_t)(s0 + l) * 8, &Wg[(size_t)s0 * 8]);
  }
  if (t < 128) {
    scs[t] = scale[t];
    shs[t] = shift[t];
  }
  __syncthreads();
#pragma unroll
  for (int k = 0; k < 4; ++k) {
    const int s = t + k * 256;  // [row 64][kb 16]
    const int row = s >> 4, kb = s & 15;
    const float4 v0 = *(const float4*)&h[(size_t)(row0 + row) * NH + kb * 8];
    const float4 v1 = *(const float4*)&h[(size_t)(row0 + row) * NH + kb * 8 + 4];
    u16 p[8];
    p[0] = f2bf(fmaxf(fmaf(v0.x, scs[kb * 8 + 0], shs[kb * 8 + 0]), 0.f));
    p[1] = f2bf(fmaxf(fmaf(v0.y, scs[kb * 8 + 1], shs[kb * 8 + 1]), 0.f));
    p[2] = f2bf(fmaxf(fmaf(v0.z, scs[kb * 8 + 2], shs[kb * 8 + 2]), 0.f));
    p[3] = f2bf(fmaxf(fmaf(v0.w, scs[kb * 8 + 3], shs[kb * 8 + 3]), 0.f));
    p[4] = f2bf(fmaxf(fmaf(v1.x, scs[kb * 8 + 4], shs[kb * 8 + 4]), 0.f));
    p[5] = f2bf(fmaxf(fmaf(v1.y, scs[kb * 8 + 5], shs[kb * 8 + 5]), 0.f));
    p[6] = f2bf(fmaxf(fmaf(v1.z, scs[kb * 8 + 6], shs[kb * 8 + 6]), 0.f));
    p[7] = f2bf(fmaxf(fmaf(v1.w, scs[kb * 8 + 7], shs[kb * 8 + 7]), 0.f));
    uint4 o;
    o.x = (u32)p[0] | ((u32)p[1] << 16);
    o.y = (u32)p[2] | ((u32)p[3] << 16);
    o.z = (u32)p[4] | ((u32)p[5] << 16);
    o.w = (u32)p[6] | ((u32)p[7] << 16);
    const int boff = (row * 256 + kb * 16) ^ ((row & 7) << 4);
    *(uint4*)&him[boff >> 1] = o;
  }
  __syncthreads();
  f32x4 acc[4];
#pragma unroll
  for (int nf = 0; nf < 4; ++nf) {
    acc[nf][0] = 0.f; acc[nf][1] = 0.f;
    acc[nf][2] = 0.f; acc[nf][3] = 0.f;
  }
#pragma unroll
  for (int kks = 0; kks < 4; ++kks) {
    const int ko = kks * 4 + lg;
    const int arow = w * 16 + lr;
    const int aoff = (arow * 256 + ko * 16) ^ ((arow & 7) << 4);
    const bf16x8 a = *(const bf16x8*)&him[aoff >> 1];
#pragma unroll
    for (int nf = 0; nf < 4; ++nf) {
      const bf16x8 bfr = *(const bf16x8*)&Wg[(ko * 64 + nf * 16 + lr) * 8];
      acc[nf] = mfma16(a, bfr, acc[nf]);
    }
  }
#pragma unroll
  for (int nf = 0; nf < 4; ++nf) {
    const int col = nf * 16 + lr;
#pragma unroll
    for (int r = 0; r < 4; ++r) {
      hos[w * 16 + lg * 4 + r][col] = f2bf(acc[nf][r]);
    }
  }
  __syncthreads();
  const size_t tbase = (size_t)blockIdx.x * 4096;
#pragma unroll
  for (int k = 0; k < 2; ++k) {
    const int s = t + k * 256;
    const int kb = s >> 6, r6 = s & 63;
    const uint2 lo = *(const uint2*)&hos[r6][kb * 8];
    const uint2 hi = *(const uint2*)&hos[r6][kb * 8 + 4];
    uint4 o;
    o.x = lo.x; o.y = lo.y; o.z = hi.x; o.w = hi.y;
    *(uint4*)&hp_sw[tbase + kb * 512 + r6 * 8] = o;
  }
}

// ---------------- attn XCD swizzle helper ------------------------------------
__device__ __forceinline__ void attn_swz(int& b, int& nt, int& qtr) {
  const int flat = blockIdx.y * 512 + blockIdx.x;  // 0..2047
  const int lf = (flat & 7) * 256 + (flat >> 3);
  b = lf >> 7;
  const int rem = lf & 127;
  qtr = rem >> 5;
  nt = rem & 31;
}

// ---------------- K_attnA: partial D over m-quarter --------------------------
__global__ __launch_bounds__(256) void k_attnA(const u16* __restrict__ hp_sw,
                                               float* __restrict__ Dpart) {
  int b, nt, qtr;
  attn_swz(b, nt, qtr);
  const int t = threadIdx.x, w = t >> 6, l = t & 63;
  const int lg = l >> 4, lr = l & 15;
  __shared__ __align__(16) u16 Cs[2][4096];
  const u16* rbase = hp_sw + (size_t)(b * 32 + nt) * 4096;
  const int qrow = (w << 4) + lr;
  const bf16x8 bq0 = *(const bf16x8*)&rbase[(lg * 64 + qrow) * 8];
  const bf16x8 bq1 = *(const bf16x8*)&rbase[((lg + 4) * 64 + qrow) * 8];
  const u16* cb = hp_sw + (size_t)(b * 32 + qtr * 8) * 4096;
#pragma unroll
  for (int i = 0; i < 2; ++i) gload16(cb + (size_t)(i * 256 + t) * 8, &Cs[0][(i * 256 + t) * 8]);
  __syncthreads();
  float S = 0.f;
  for (int mt = 0; mt < 8; ++mt) {
    const int cur = mt & 1;
    if (mt + 1 < 8) {
#pragma unroll
      for (int i = 0; i < 2; ++i)
        gload16(cb + (size_t)(mt + 1) * 4096 + (size_t)(i * 256 + t) * 8,
                &Cs[cur ^ 1][(i * 256 + t) * 8]);
    }
#pragma unroll
    for (int mf = 0; mf < 4; ++mf) {
      const bf16x8 a0 = *(const bf16x8*)&Cs[cur][(lg * 64 + mf * 16 + lr) * 8];
      const bf16x8 a1 = *(const bf16x8*)&Cs[cur][((lg + 4) * 64 + mf * 16 + lr) * 8];
      f32x4 z;
      z[0] = 0.f; z[1] = 0.f; z[2] = 0.f; z[3] = 0.f;
      z = mfma16(a0, bq0, z);
      z = mfma16(a1, bq1, z);
      S += explr(z[0]) + explr(z[1]) + explr(z[2]) + explr(z[3]);
    }
    __syncthreads();
  }
  S += __shfl_xor(S, 16);
  S += __shfl_xor(S, 32);
  if (l < 16) Dpart[qtr * 32768 + b * NN + nt * 64 + qrow] = S;
}

// ---------------- K_attnB: partial S (computes iD in-block) ------------------
__global__ __launch_bounds__(256) void k_attnB(const u16* __restrict__ hp_sw,
                                               const float* __restrict__ Dpart,
                                               float* __restrict__ Spart) {
  int b, nt, qtr;
  attn_swz(b, nt, qtr);
  const int t = threadIdx.x, w = t >> 6, l = t & 63;
  const int lg = l >> 4, lr = l & 15;
  __shared__ __align__(16) u16 Cs[2][4096];
  __shared__ float iDs[512];
  const u16* rbase = hp_sw + (size_t)(b * 32 + nt) * 4096;
  const int qrow = (w << 4) + lr;
  const bf16x8 bq0 = *(const bf16x8*)&rbase[(lg * 64 + qrow) * 8];
  const bf16x8 bq1 = *(const bf16x8*)&rbase[((lg + 4) * 64 + qrow) * 8];
  const u16* cb = hp_sw + (size_t)(b * 32 + qtr * 8) * 4096;
#pragma unroll
  for (int i = 0; i < 2; ++i) gload16(cb + (size_t)(i * 256 + t) * 8, &Cs[0][(i * 256 + t) * 8]);
#pragma unroll
  for (int i = 0; i < 2; ++i) {
    const int idx = t + i * 256;
    const int n = b * NN + qtr * 512 + idx;
    iDs[idx] = 1.f / (Dpart[n] + Dpart[32768 + n] + Dpart[65536 + n] + Dpart[98304 + n]);
  }
  __syncthreads();
  float S = 0.f;
  for (int mt = 0; mt < 8; ++mt) {
    const int cur = mt & 1;
    if (mt + 1 < 8) {
#pragma unroll
      for (int i = 0; i < 2; ++i)
        gload16(cb + (size_t)(mt + 1) * 4096 + (size_t)(i * 256 + t) * 8,
                &Cs[cur ^ 1][(i * 256 + t) * 8]);
    }
#pragma unroll
    for (int mf = 0; mf < 4; ++mf) {
      const bf16x8 a0 = *(const bf16x8*)&Cs[cur][(lg * 64 + mf * 16 + lr) * 8];
      const bf16x8 a1 = *(const bf16x8*)&Cs[cur][((lg + 4) * 64 + mf * 16 + lr) * 8];
      f32x4 z;
      z[0] = 0.f; z[1] = 0.f; z[2] = 0.f; z[3] = 0.f;
      z = mfma16(a0, bq0, z);
      z = mfma16(a1, bq1, z);
      const float4 dv = *(const float4*)&iDs[mt * 64 + mf * 16 + lg * 4];
      S = fmaf(explr(z[0]), dv.x, S);
      S = fmaf(explr(z[1]), dv.y, S);
      S = fmaf(explr(z[2]), dv.z, S);
      S = fmaf(explr(z[3]), dv.w, S);
    }
    __syncthreads();
  }
  S += __shfl_xor(S, 16);
  S += __shfl_xor(S, 32);
  if (l < 16) Spart[qtr * 32768 + b * NN + nt * 64 + qrow] = S;
}

// ---------------- K_scale: out = hp * (S0+S1+S2+S3) --------------------------
__global__ __launch_bounds__(256) void k_scale(const u16* __restrict__ hp_sw,
                                               const float* __restrict__ Spart,
                                               float* __restrict__ out) {
  const int bx = blockIdx.x;
  const int b = bx >> 5, nt = bx & 31;
  const int t = threadIdx.x;
  __shared__ float Sv[64];
  if (t < 64) {
    const int n = b * NN + nt * 64 + t;
    Sv[t] = Spart[n] + Spart[32768 + n] + Spart[65536 + n] + Spart[98304 + n];
  }
  __syncthreads();
  const u16* rbase = hp_sw + (size_t)(b * 32 + nt) * 4096;
  const int row = t >> 2;
  const float sc = Sv[row];
  const size_t R = (size_t)b * NN + nt * 64 + row;
#pragma unroll
  for (int hh = 0; hh < 2; ++hh) {
    const int kb = (t & 3) * 2 + hh;
    const u16* src = &rbase[(kb * 64 + row) * 8];
    float4 o0, o1;
    o0.x = bf2f(src[0]) * sc;
    o0.y = bf2f(src[1]) * sc;
    o0.z = bf2f(src[2]) * sc;
    o0.w = bf2f(src[3]) * sc;
    o1.x = bf2f(src[4]) * sc;
    o1.y = bf2f(src[5]) * sc;
    o1.z = bf2f(src[6]) * sc;
    o1.w = bf2f(src[7]) * sc;
    *(float4*)&out[R * NO + kb * 8] = o0;
    *(float4*)&out[R * NO + kb * 8 + 4] = o1;
  }
}

extern "C" void kernel_launch(void* const* d_in, const int* in_sizes, int n_in,
                              void* d_out, int out_size, void* d_ws, size_t ws_size,
                              hipStream_t stream) {
  const float* x = (const float*)d_in[0];
  // d_in[1] = adj (unused)
  const float* adj_gcn = (const float*)d_in[2];
  const float* gcn_w = (const float*)d_in[3];
  const float* gcn_b = (const float*)d_in[4];
  const float* gamma = (const float*)d_in[5];
  const float* beta = (const float*)d_in[6];
  const float* gat_w = (const float*)d_in[7];
  float* out = (float*)d_out;
  float* ws = (float*)d_ws;

  // workspace layout (float units):
  u16* adj_sw = (u16*)ws;                  // [0, 2M)
  u16* suppT_sw = (u16*)(ws + 2097152);    // [2M, 4M)
  float* hbuf = ws + 4194304;              // [4M, 8M)
  u16* hp_sw = (u16*)(ws + 8388608);       // [8M, 9M)
  float* psum = ws + 9437184;              // 65536
  float* psq = psum + 65536;               // 65536
  float* scale = psq + 65536;              // 128
  float* shift = scale + 128;              // 128
  u16* Wg_sw = (u16*)(shift + 128);        // 8192 u16 (4096 f)
  float* Dpart = ws + 9617664;             // 131072
  float* Spart = Dpart + 131072;           // 131072

  k_prep<<<dim3(1537), dim3(256), 0, stream>>>(x, adj_gcn, gcn_w, gat_w, suppT_sw, adj_sw, Wg_sw);
  k_gcn<<<dim3(32, 16), dim3(512), 0, stream>>>(adj_sw, suppT_sw, gcn_b, hbuf, psum, psq);
  k_bnstat2<<<dim3(1), dim3(1024), 0, stream>>>(psum, psq, gamma, beta, scale, shift);
  k_hp<<<dim3(512), dim3(256), 0, stream>>>(hbuf, scale, shift, Wg_sw, hp_sw);
  k_attnA<<<dim3(512, 4), dim3(256), 0, stream>>>(hp_sw, Dpart);
  k_attnB<<<dim3(512, 4), dim3(256), 0, stream>>>(hp_sw, Dpart, Spart);
  k_scale<<<dim3(512), dim3(256), 0, stream>>>(hp_sw, Spart, out);
}

// Round 13
// 110.280 us; speedup vs baseline: 3.5722x; 1.0085x over previous
//
#include <hip/hip_runtime.h>
#include <math.h>

#define NB 16
#define NN 2048
#define NF 128
#define NH 128
#define NO 64

typedef short bf16x8 __attribute__((ext_vector_type(8)));
typedef float f32x4 __attribute__((ext_vector_type(4)));
typedef unsigned short u16;
typedef unsigned int u32;

#define LOG2E 1.4426950408889634f
#define EXPSHIFT 43.28085122666891f  // 30 * log2(e)

__device__ __forceinline__ u16 f2bf(float f) {
  u32 u = __builtin_bit_cast(u32, f);
  return (u16)((u + 0x7fffu + ((u >> 16) & 1u)) >> 16);
}
__device__ __forceinline__ float bf2f(u16 h) {
  u32 u = ((u32)h) << 16;
  return __builtin_bit_cast(float, u);
}

__device__ __forceinline__ void gload16(const void* g, void* l) {
  __builtin_amdgcn_global_load_lds((const __attribute__((address_space(1))) void*)g,
                                   (__attribute__((address_space(3))) void*)l, 16, 0, 0);
}
__device__ __forceinline__ f32x4 mfma16(bf16x8 a, bf16x8 b, f32x4 c) {
  return __builtin_amdgcn_mfma_f32_16x16x32_bf16(a, b, c, 0, 0, 0);
}
// exp(lrelu(z) - 30): max, mul, fma, v_exp
__device__ __forceinline__ float explr(float z) {
  return __builtin_amdgcn_exp2f(fmaf(fmaxf(z, 0.2f * z), LOG2E, -EXPSHIFT));
}

// ---------------- K_prep: Wg + adj swizzle + support GEMM, one launch --------
// bid 0        : Wg_sw = gat_w bf16 [kblk 16][col 64][8]
// bid 1..1024  : adj_sw = adj bf16 [ntile 32][ktile 32][kblk 8][row 64][8]
// bid 1025..1536: support: one 64-row ktile of (x @ W)^T, W self-cast from L2
__global__ __launch_bounds__(256) void k_prep(const float* __restrict__ x,
                                              const float* __restrict__ adj,
                                              const float* __restrict__ gcn_w,
                                              const float* __restrict__ gat_w,
                                              u16* __restrict__ suppT_sw,
                                              u16* __restrict__ adj_sw,
                                              u16* __restrict__ Wg_sw) {
  __shared__ __align__(16) u16 ts[64 * 136];  // 17.4KB
  __shared__ __align__(16) u16 Bs[16384];     // 32KB W image; reused as os
  const int t = threadIdx.x;
  const int bid = blockIdx.x;
  if (bid == 0) {
#pragma unroll
    for (int it = 0; it < 4; ++it) {
      const int s = t + it * 256;  // [kb 16][col 64]
      const int kb = s >> 6, col = s & 63;
      u16 tmp[8];
#pragma unroll
      for (int j = 0; j < 8; ++j) tmp[j] = f2bf(gat_w[(kb * 8 + j) * 64 + col]);
      uint4 o;
      o.x = (u32)tmp[0] | ((u32)tmp[1] << 16);
      o.y = (u32)tmp[2] | ((u32)tmp[3] << 16);
      o.z = (u32)tmp[4] | ((u32)tmp[5] << 16);
      o.w = (u32)tmp[6] | ((u32)tmp[7] << 16);
      *(uint4*)&Wg_sw[(size_t)s * 8] = o;
    }
  } else if (bid < 1025) {
    const int tile = bid - 1;  // [nt 32][kt 32]
    const int n0 = (tile >> 5) * 64, m0 = (tile & 31) * 64;
#pragma unroll
    for (int k = 0; k < 4; ++k) {
      const int s = t + k * 256;  // 1024 float4 slots
      const int row = s >> 4, c4 = (s & 15) * 4;
      const float4 f = *(const float4*)&adj[(size_t)(n0 + row) * 2048 + m0 + c4];
      uint2 pk;
      pk.x = (u32)f2bf(f.x) | ((u32)f2bf(f.y) << 16);
      pk.y = (u32)f2bf(f.z) | ((u32)f2bf(f.w) << 16);
      *(uint2*)&ts[row * 136 + c4] = pk;
    }
    __syncthreads();
#pragma unroll
    for (int k = 0; k < 2; ++k) {
      const int s = t + k * 256;  // [kb 8][row 64]
      const int kb = s >> 6, row = s & 63;
      const uint4 v = *(const uint4*)&ts[row * 136 + kb * 8];
      *(uint4*)&adj_sw[(size_t)tile * 4096 + (size_t)s * 8] = v;
    }
  } else {
    const int sb = bid - 1025;  // 0..511
    const int m0g = sb * 64;
    const int w = t >> 6, l = t & 63;
    const int lg = l >> 4, lr = l & 15;
    // self-cast W image: Bs[kb 16][d 128][8] = gcn_w[kb*8+j][d]
#pragma unroll
    for (int i = 0; i < 8; ++i) {
      const int s = t + i * 256;
      const int kb = s >> 7, d = s & 127;
      u16 tmp[8];
#pragma unroll
      for (int j = 0; j < 8; ++j) tmp[j] = f2bf(gcn_w[(kb * 8 + j) * 128 + d]);
      uint4 o;
      o.x = (u32)tmp[0] | ((u32)tmp[1] << 16);
      o.y = (u32)tmp[2] | ((u32)tmp[3] << 16);
      o.z = (u32)tmp[4] | ((u32)tmp[5] << 16);
      o.w = (u32)tmp[6] | ((u32)tmp[7] << 16);
      *(uint4*)&Bs[(size_t)s * 8] = o;
    }
    // x tile 64x128 -> ts (row stride 136)
#pragma unroll
    for (int k = 0; k < 8; ++k) {
      const int s = t + k * 256;  // [row 64][c4 32]
      const int row = s >> 5, c4 = (s & 31) * 4;
      const float4 f = *(const float4*)&x[(size_t)(m0g + row) * 128 + c4];
      uint2 pk;
      pk.x = (u32)f2bf(f.x) | ((u32)f2bf(f.y) << 16);
      pk.y = (u32)f2bf(f.z) | ((u32)f2bf(f.w) << 16);
      *(uint2*)&ts[row * 136 + c4] = pk;
    }
    __syncthreads();
    f32x4 acc[8];
#pragma unroll
    for (int nf = 0; nf < 8; ++nf) {
      acc[nf][0] = 0.f; acc[nf][1] = 0.f;
      acc[nf][2] = 0.f; acc[nf][3] = 0.f;
    }
#pragma unroll
    for (int ks = 0; ks < 4; ++ks) {
      const int kb = ks * 4 + lg;
      const bf16x8 a = *(const bf16x8*)&ts[(w * 16 + lr) * 136 + kb * 8];
#pragma unroll
      for (int nf = 0; nf < 8; ++nf) {
        const bf16x8 bb = *(const bf16x8*)&Bs[((size_t)kb * 128 + nf * 16 + lr) * 8];
        acc[nf] = mfma16(a, bb, acc[nf]);
      }
    }
    __syncthreads();
    u16* os = Bs;  // transpose: os[d 128][m 64], stride 72 u16
#pragma unroll
    for (int nf = 0; nf < 8; ++nf) {
      const int d = nf * 16 + lr;
      const int mb = w * 16 + lg * 4;
      const u32 p0 = (u32)f2bf(acc[nf][0]) | ((u32)f2bf(acc[nf][1]) << 16);
      const u32 p1 = (u32)f2bf(acc[nf][2]) | ((u32)f2bf(acc[nf][3]) << 16);
      *(u32*)&os[d * 72 + mb] = p0;
      *(u32*)&os[d * 72 + mb + 2] = p1;
    }
    __syncthreads();
    const int b = m0g >> 11, mt = (m0g & 2047) >> 6;
#pragma unroll
    for (int i = 0; i < 4; ++i) {
      const int s = i * 256 + t;  // [kb 8][d 128]
      const int kb = s >> 7, d = s & 127;
      const uint4 v = *(const uint4*)&os[d * 72 + kb * 8];
      *(uint4*)&suppT_sw[((size_t)((b * 32 + mt) * 8 + kb)) * 1024 + (size_t)d * 8] = v;
    }
  }
}

// ---------------- K_gcn: 64x128 tile, BK=64, 8 waves, XCD-swizzled -----------
__global__ __launch_bounds__(512) void k_gcn(const u16* __restrict__ adj_sw,
                                             const u16* __restrict__ suppT_sw,
                                             const float* __restrict__ bias,
                                             float* __restrict__ h,
                                             float* __restrict__ psum,
                                             float* __restrict__ psq) {
  const int flat = blockIdx.y * 32 + blockIdx.x;  // 0..511
  const int nf2 = (flat & 7) * 64 + (flat >> 3);  // XCD swizzle
  const int b = nf2 >> 5, nt = nf2 & 31;
  const int n0 = nt * 64;
  const int t = threadIdx.x;
  const int w = t >> 6, l = t & 63;
  const int wm = w >> 1, wn = w & 1;
  const int lg = l >> 4, lr = l & 15;
  __shared__ __align__(16) u16 As[2][4096];
  __shared__ __align__(16) u16 Bs[2][8192];
  __shared__ float redS[4][128], redQ[4][128];

  f32x4 acc[4];
#pragma unroll
  for (int nf = 0; nf < 4; ++nf) {
    acc[nf][0] = 0.f; acc[nf][1] = 0.f;
    acc[nf][2] = 0.f; acc[nf][3] = 0.f;
  }

#define GCN_STAGE(buf, kt)                                                        \
  {                                                                               \
    gload16(adj_sw + ((size_t)(nt * 32 + (kt))) * 4096 + (size_t)t * 8,           \
            &As[buf][t * 8]);                                                     \
    _Pragma("unroll") for (int i = 0; i < 2; ++i) {                               \
      const int s = i * 512 + t;                                                  \
      gload16(suppT_sw + ((size_t)(b * 32 + (kt))) * 8192 + (size_t)s * 8,        \
              &Bs[buf][s * 8]);                                                   \
    }                                                                             \
  }

  GCN_STAGE(0, 0);
  __syncthreads();
  for (int kt = 0; kt < 32; ++kt) {
    const int cur = kt & 1;
    if (kt + 1 < 32) GCN_STAGE(cur ^ 1, kt + 1);
#pragma unroll
    for (int kb = 0; kb < 2; ++kb) {
      const int ko = kb * 4 + lg;
      const bf16x8 a0 = *(const bf16x8*)&As[cur][(ko * 64 + wm * 16 + lr) * 8];
      const bf16x8 b0 = *(const bf16x8*)&Bs[cur][(ko * 128 + wn * 64 + lr) * 8];
      const bf16x8 b1 = *(const bf16x8*)&Bs[cur][(ko * 128 + wn * 64 + 16 + lr) * 8];
      const bf16x8 b2 = *(const bf16x8*)&Bs[cur][(ko * 128 + wn * 64 + 32 + lr) * 8];
      const bf16x8 b3 = *(const bf16x8*)&Bs[cur][(ko * 128 + wn * 64 + 48 + lr) * 8];
      acc[0] = mfma16(a0, b0, acc[0]);
      acc[1] = mfma16(a0, b1, acc[1]);
      acc[2] = mfma16(a0, b2, acc[2]);
      acc[3] = mfma16(a0, b3, acc[3]);
    }
    __syncthreads();
  }
#undef GCN_STAGE
#pragma unroll
  for (int nf = 0; nf < 4; ++nf) {
    const int d = wn * 64 + nf * 16 + lr;
    const float bv = bias[d];
    float s = 0.f, q = 0.f;
#pragma unroll
    for (int r = 0; r < 4; ++r) {
      const float v = acc[nf][r] + bv;
      const int row = n0 + wm * 16 + lg * 4 + r;
      h[((size_t)(b * NN + row)) * NH + d] = v;
      s += v;
      q = fmaf(v, v, q);
    }
    s += __shfl_xor(s, 16);
    s += __shfl_xor(s, 32);
    q += __shfl_xor(q, 16);
    q += __shfl_xor(q, 32);
    if (lg == 0) {
      redS[wm][d] = s;
      redQ[wm][d] = q;
    }
  }
  __syncthreads();
  if (t < 128) {
    const int blk = b * 32 + nt;
    psum[blk * 128 + t] = redS[0][t] + redS[1][t] + redS[2][t] + redS[3][t];
    psq[blk * 128 + t] = redQ[0][t] + redQ[1][t] + redQ[2][t] + redQ[3][t];
  }
}

// ---------------- BN finalize ------------------------------------------------
__global__ __launch_bounds__(1024) void k_bnstat2(const float* __restrict__ psum,
                                                  const float* __restrict__ psq,
                                                  const float* __restrict__ gamma,
                                                  const float* __restrict__ beta,
                                                  float* __restrict__ scale,
                                                  float* __restrict__ shift) {
  const int t = threadIdx.x;
  const int d = t & 127;
  const int g = t >> 7;
  float s = 0.f, q = 0.f;
  for (int i = g; i < 512; i += 8) {
    s += psum[i * 128 + d];
    q += psq[i * 128 + d];
  }
  __shared__ float ls[8][128], lq[8][128];
  ls[g][d] = s;
  lq[g][d] = q;
  __syncthreads();
  if (t < 128) {
    s = 0.f;
    q = 0.f;
#pragma unroll
    for (int i = 0; i < 8; ++i) {
      s += ls[i][t];
      q += lq[i][t];
    }
    const float inv = 1.f / (float)(NB * NN);
    const float mean = s * inv;
    const float var = q * inv - mean * mean;
    const float sc = gamma[t] * rsqrtf(var + 1e-5f);
    scale[t] = sc;
    shift[t] = beta[t] - mean * sc;
  }
}

// ---------------- K_hp: MFMA version -----------------------------------------
__global__ __launch_bounds__(256) void k_hp(const float* __restrict__ h,
                                            const float* __restrict__ scale,
                                            const float* __restrict__ shift,
                                            const u16* __restrict__ Wg_sw,
                                            u16* __restrict__ hp_sw) {
  const int row0 = blockIdx.x * 64;
  const int t = threadIdx.x, w = t >> 6, l = t & 63;
  const int lg = l >> 4, lr = l & 15;
  __shared__ __align__(16) u16 him[8192];
  __shared__ __align__(16) u16 Wg[8192];
  __shared__ __align__(16) u16 hos[64][72];
  __shared__ float scs[128], shs[128];
#pragma unroll
  for (int i = 0; i < 4; ++i) {
    const int s0 = i * 256 + w * 64;
    gload16(Wg_sw + (size_t)(s0 + l) * 8, &Wg[(size_t)s0 * 8]);
  }
  if (t < 128) {
    scs[t] = scale[t];
    shs[t] = shift[t];
  }
  __syncthreads();
#pragma unroll
  for (int k = 0; k < 4; ++k) {
    const int s = t + k * 256;  // [row 64][kb 16]
    const int row = s >> 4, kb = s & 15;
    const float4 v0 = *(const float4*)&h[(size_t)(row0 + row) * NH + kb * 8];
    const float4 v1 = *(const float4*)&h[(size_t)(row0 + row) * NH + kb * 8 + 4];
    u16 p[8];
    p[0] = f2bf(fmaxf(fmaf(v0.x, scs[kb * 8 + 0], shs[kb * 8 + 0]), 0.f));
    p[1] = f2bf(fmaxf(fmaf(v0.y, scs[kb * 8 + 1], shs[kb * 8 + 1]), 0.f));
    p[2] = f2bf(fmaxf(fmaf(v0.z, scs[kb * 8 + 2], shs[kb * 8 + 2]), 0.f));
    p[3] = f2bf(fmaxf(fmaf(v0.w, scs[kb * 8 + 3], shs[kb * 8 + 3]), 0.f));
    p[4] = f2bf(fmaxf(fmaf(v1.x, scs[kb * 8 + 4], shs[kb * 8 + 4]), 0.f));
    p[5] = f2bf(fmaxf(fmaf(v1.y, scs[kb * 8 + 5], shs[kb * 8 + 5]), 0.f));
    p[6] = f2bf(fmaxf(fmaf(v1.z, scs[kb * 8 + 6], shs[kb * 8 + 6]), 0.f));
    p[7] = f2bf(fmaxf(fmaf(v1.w, scs[kb * 8 + 7], shs[kb * 8 + 7]), 0.f));
    uint4 o;
    o.x = (u32)p[0] | ((u32)p[1] << 16);
    o.y = (u32)p[2] | ((u32)p[3] << 16);
    o.z = (u32)p[4] | ((u32)p[5] << 16);
    o.w = (u32)p[6] | ((u32)p[7] << 16);
    const int boff = (row * 256 + kb * 16) ^ ((row & 7) << 4);
    *(uint4*)&him[boff >> 1] = o;
  }
  __syncthreads();
  f32x4 acc[4];
#pragma unroll
  for (int nf = 0; nf < 4; ++nf) {
    acc[nf][0] = 0.f; acc[nf][1] = 0.f;
    acc[nf][2] = 0.f; acc[nf][3] = 0.f;
  }
#pragma unroll
  for (int kks = 0; kks < 4; ++kks) {
    const int ko = kks * 4 + lg;
    const int arow = w * 16 + lr;
    const int aoff = (arow * 256 + ko * 16) ^ ((arow & 7) << 4);
    const bf16x8 a = *(const bf16x8*)&him[aoff >> 1];
#pragma unroll
    for (int nf = 0; nf < 4; ++nf) {
      const bf16x8 bfr = *(const bf16x8*)&Wg[(ko * 64 + nf * 16 + lr) * 8];
      acc[nf] = mfma16(a, bfr, acc[nf]);
    }
  }
#pragma unroll
  for (int nf = 0; nf < 4; ++nf) {
    const int col = nf * 16 + lr;
#pragma unroll
    for (int r = 0; r < 4; ++r) {
      hos[w * 16 + lg * 4 + r][col] = f2bf(acc[nf][r]);
    }
  }
  __syncthreads();
  const size_t tbase = (size_t)blockIdx.x * 4096;
#pragma unroll
  for (int k = 0; k < 2; ++k) {
    const int s = t + k * 256;
    const int kb = s >> 6, r6 = s & 63;
    const uint2 lo = *(const uint2*)&hos[r6][kb * 8];
    const uint2 hi = *(const uint2*)&hos[r6][kb * 8 + 4];
    uint4 o;
    o.x = lo.x; o.y = lo.y; o.z = hi.x; o.w = hi.y;
    *(uint4*)&hp_sw[tbase + kb * 512 + r6 * 8] = o;
  }
}

// ---------------- attn XCD swizzle helper ------------------------------------
__device__ __forceinline__ void attn_swz(int& b, int& nt, int& qtr) {
  const int flat = blockIdx.y * 512 + blockIdx.x;  // 0..2047
  const int lf = (flat & 7) * 256 + (flat >> 3);
  b = lf >> 7;
  const int rem = lf & 127;
  qtr = rem >> 5;
  nt = rem & 31;
}

// ---------------- K_attnA: partial D, direct L2 fragment loads (no LDS) ------
__global__ __launch_bounds__(256) void k_attnA(const u16* __restrict__ hp_sw,
                                               float* __restrict__ Dpart) {
  int b, nt, qtr;
  attn_swz(b, nt, qtr);
  const int t = threadIdx.x, w = t >> 6, l = t & 63;
  const int lg = l >> 4, lr = l & 15;
  const u16* rbase = hp_sw + (size_t)(b * 32 + nt) * 4096;
  const int qrow = (w << 4) + lr;
  const bf16x8 bq0 = *(const bf16x8*)&rbase[(lg * 64 + qrow) * 8];
  const bf16x8 bq1 = *(const bf16x8*)&rbase[((lg + 4) * 64 + qrow) * 8];
  const u16* cb = hp_sw + (size_t)(b * 32 + qtr * 8) * 4096;
  float S = 0.f;
#pragma unroll 2
  for (int mt = 0; mt < 8; ++mt) {
    const u16* base = cb + (size_t)mt * 4096;
#pragma unroll
    for (int mf = 0; mf < 4; ++mf) {
      const bf16x8 a0 = *(const bf16x8*)&base[(lg * 64 + mf * 16 + lr) * 8];
      const bf16x8 a1 = *(const bf16x8*)&base[((lg + 4) * 64 + mf * 16 + lr) * 8];
      f32x4 z;
      z[0] = 0.f; z[1] = 0.f; z[2] = 0.f; z[3] = 0.f;
      __builtin_amdgcn_s_setprio(1);
      z = mfma16(a0, bq0, z);
      z = mfma16(a1, bq1, z);
      __builtin_amdgcn_s_setprio(0);
      S += explr(z[0]) + explr(z[1]) + explr(z[2]) + explr(z[3]);
    }
  }
  S += __shfl_xor(S, 16);
  S += __shfl_xor(S, 32);
  if (l < 16) Dpart[qtr * 32768 + b * NN + nt * 64 + qrow] = S;
}

// ---------------- K_attnB: partial S, direct L2 fragment loads ---------------
__global__ __launch_bounds__(256) void k_attnB(const u16* __restrict__ hp_sw,
                                               const float* __restrict__ Dpart,
                                               float* __restrict__ Spart) {
  int b, nt, qtr;
  attn_swz(b, nt, qtr);
  const int t = threadIdx.x, w = t >> 6, l = t & 63;
  const int lg = l >> 4, lr = l & 15;
  __shared__ float iDs[512];
  const u16* rbase = hp_sw + (size_t)(b * 32 + nt) * 4096;
  const int qrow = (w << 4) + lr;
  const bf16x8 bq0 = *(const bf16x8*)&rbase[(lg * 64 + qrow) * 8];
  const bf16x8 bq1 = *(const bf16x8*)&rbase[((lg + 4) * 64 + qrow) * 8];
  const u16* cb = hp_sw + (size_t)(b * 32 + qtr * 8) * 4096;
#pragma unroll
  for (int i = 0; i < 2; ++i) {
    const int idx = t + i * 256;
    const int n = b * NN + qtr * 512 + idx;
    iDs[idx] = 1.f / (Dpart[n] + Dpart[32768 + n] + Dpart[65536 + n] + Dpart[98304 + n]);
  }
  __syncthreads();
  float S = 0.f;
#pragma unroll 2
  for (int mt = 0; mt < 8; ++mt) {
    const u16* base = cb + (size_t)mt * 4096;
#pragma unroll
    for (int mf = 0; mf < 4; ++mf) {
      const bf16x8 a0 = *(const bf16x8*)&base[(lg * 64 + mf * 16 + lr) * 8];
      const bf16x8 a1 = *(const bf16x8*)&base[((lg + 4) * 64 + mf * 16 + lr) * 8];
      f32x4 z;
      z[0] = 0.f; z[1] = 0.f; z[2] = 0.f; z[3] = 0.f;
      __builtin_amdgcn_s_setprio(1);
      z = mfma16(a0, bq0, z);
      z = mfma16(a1, bq1, z);
      __builtin_amdgcn_s_setprio(0);
      const float4 dv = *(const float4*)&iDs[mt * 64 + mf * 16 + lg * 4];
      S = fmaf(explr(z[0]), dv.x, S);
      S = fmaf(explr(z[1]), dv.y, S);
      S = fmaf(explr(z[2]), dv.z, S);
      S = fmaf(explr(z[3]), dv.w, S);
    }
  }
  S += __shfl_xor(S, 16);
  S += __shfl_xor(S, 32);
  if (l < 16) Spart[qtr * 32768 + b * NN + nt * 64 + qrow] = S;
}

// ---------------- K_scale: out = hp * (S0+S1+S2+S3) --------------------------
__global__ __launch_bounds__(256) void k_scale(const u16* __restrict__ hp_sw,
                                               const float* __restrict__ Spart,
                                               float* __restrict__ out) {
  const int bx = blockIdx.x;
  const int b = bx >> 5, nt = bx & 31;
  const int t = threadIdx.x;
  __shared__ float Sv[64];
  if (t < 64) {
    const int n = b * NN + nt * 64 + t;
    Sv[t] = Spart[n] + Spart[32768 + n] + Spart[65536 + n] + Spart[98304 + n];
  }
  __syncthreads();
  const u16* rbase = hp_sw + (size_t)(b * 32 + nt) * 4096;
  const int row = t >> 2;
  const float sc = Sv[row];
  const size_t R = (size_t)b * NN + nt * 64 + row;
#pragma unroll
  for (int hh = 0; hh < 2; ++hh) {
    const int kb = (t & 3) * 2 + hh;
    const uint4 v = *(const uint4*)&rbase[(kb * 64 + row) * 8];
    float4 o0, o1;
    o0.x = bf2f((u16)(v.x & 0xffff)) * sc;
    o0.y = bf2f((u16)(v.x >> 16)) * sc;
    o0.z = bf2f((u16)(v.y & 0xffff)) * sc;
    o0.w = bf2f((u16)(v.y >> 16)) * sc;
    o1.x = bf2f((u16)(v.z & 0xffff)) * sc;
    o1.y = bf2f((u16)(v.z >> 16)) * sc;
    o1.z = bf2f((u16)(v.w & 0xffff)) * sc;
    o1.w = bf2f((u16)(v.w >> 16)) * sc;
    *(float4*)&out[R * NO + kb * 8] = o0;
    *(float4*)&out[R * NO + kb * 8 + 4] = o1;
  }
}

extern "C" void kernel_launch(void* const* d_in, const int* in_sizes, int n_in,
                              void* d_out, int out_size, void* d_ws, size_t ws_size,
                              hipStream_t stream) {
  const float* x = (const float*)d_in[0];
  // d_in[1] = adj (unused)
  const float* adj_gcn = (const float*)d_in[2];
  const float* gcn_w = (const float*)d_in[3];
  const float* gcn_b = (const float*)d_in[4];
  const float* gamma = (const float*)d_in[5];
  const float* beta = (const float*)d_in[6];
  const float* gat_w = (const float*)d_in[7];
  float* out = (float*)d_out;
  float* ws = (float*)d_ws;

  // workspace layout (float units):
  u16* adj_sw = (u16*)ws;                  // [0, 2M)
  u16* suppT_sw = (u16*)(ws + 2097152);    // [2M, 4M)
  float* hbuf = ws + 4194304;              // [4M, 8M)
  u16* hp_sw = (u16*)(ws + 8388608);       // [8M, 9M)
  float* psum = ws + 9437184;              // 65536
  float* psq = psum + 65536;               // 65536
  float* scale = psq + 65536;              // 128
  float* shift = scale + 128;              // 128
  u16* Wg_sw = (u16*)(shift + 128);        // 8192 u16 (4096 f)
  float* Dpart = ws + 9617664;             // 131072
  float* Spart = Dpart + 131072;           // 131072

  k_prep<<<dim3(1537), dim3(256), 0, stream>>>(x, adj_gcn, gcn_w, gat_w, suppT_sw, adj_sw, Wg_sw);
  k_gcn<<<dim3(32, 16), dim3(512), 0, stream>>>(adj_sw, suppT_sw, gcn_b, hbuf, psum, psq);
  k_bnstat2<<<dim3(1), dim3(1024), 0, stream>>>(psum, psq, gamma, beta, scale, shift);
  k_hp<<<dim3(512), dim3(256), 0, stream>>>(hbuf, scale, shift, Wg_sw, hp_sw);
  k_attnA<<<dim3(512, 4), dim3(256), 0, stream>>>(hp_sw, Dpart);
  k_attnB<<<dim3(512, 4), dim3(256), 0, stream>>>(hp_sw, Dpart, Spart);
  k_scale<<<dim3(512), dim3(256), 0, stream>>>(hp_sw, Spart, out);
}

// Round 14
// 107.199 us; speedup vs baseline: 3.6749x; 1.0287x over previous
//
#include <hip/hip_runtime.h>
#include <math.h>

#define NB 16
#define NN 2048
#define NF 128
#define NH 128
#define NO 64

typedef short bf16x8 __attribute__((ext_vector_type(8)));
typedef float f32x4 __attribute__((ext_vector_type(4)));
typedef unsigned short u16;
typedef unsigned int u32;

#define LOG2E 1.4426950408889634f
#define EXPSHIFT 43.28085122666891f  // 30 * log2(e)

__device__ __forceinline__ u16 f2bf(float f) {
  u32 u = __builtin_bit_cast(u32, f);
  return (u16)((u + 0x7fffu + ((u >> 16) & 1u)) >> 16);
}
__device__ __forceinline__ float bf2f(u16 h) {
  u32 u = ((u32)h) << 16;
  return __builtin_bit_cast(float, u);
}

__device__ __forceinline__ void gload16(const void* g, void* l) {
  __builtin_amdgcn_global_load_lds((const __attribute__((address_space(1))) void*)g,
                                   (__attribute__((address_space(3))) void*)l, 16, 0, 0);
}
__device__ __forceinline__ f32x4 mfma16(bf16x8 a, bf16x8 b, f32x4 c) {
  return __builtin_amdgcn_mfma_f32_16x16x32_bf16(a, b, c, 0, 0, 0);
}
// exp(lrelu(z) - 30): max, mul, fma, v_exp
__device__ __forceinline__ float explr(float z) {
  return __builtin_amdgcn_exp2f(fmaf(fmaxf(z, 0.2f * z), LOG2E, -EXPSHIFT));
}

// ---------------- K_prep: Wg + adj swizzle + support GEMM, one launch --------
__global__ __launch_bounds__(256) void k_prep(const float* __restrict__ x,
                                              const float* __restrict__ adj,
                                              const float* __restrict__ gcn_w,
                                              const float* __restrict__ gat_w,
                                              u16* __restrict__ suppT_sw,
                                              u16* __restrict__ adj_sw,
                                              u16* __restrict__ Wg_sw) {
  __shared__ __align__(16) u16 ts[64 * 136];  // 17.4KB
  __shared__ __align__(16) u16 Bs[16384];     // 32KB W image; reused as os
  const int t = threadIdx.x;
  const int bid = blockIdx.x;
  if (bid == 0) {
#pragma unroll
    for (int it = 0; it < 4; ++it) {
      const int s = t + it * 256;  // [kb 16][col 64]
      const int kb = s >> 6, col = s & 63;
      u16 tmp[8];
#pragma unroll
      for (int j = 0; j < 8; ++j) tmp[j] = f2bf(gat_w[(kb * 8 + j) * 64 + col]);
      uint4 o;
      o.x = (u32)tmp[0] | ((u32)tmp[1] << 16);
      o.y = (u32)tmp[2] | ((u32)tmp[3] << 16);
      o.z = (u32)tmp[4] | ((u32)tmp[5] << 16);
      o.w = (u32)tmp[6] | ((u32)tmp[7] << 16);
      *(uint4*)&Wg_sw[(size_t)s * 8] = o;
    }
  } else if (bid < 1025) {
    const int tile = bid - 1;  // [nt 32][kt 32]
    const int n0 = (tile >> 5) * 64, m0 = (tile & 31) * 64;
#pragma unroll
    for (int k = 0; k < 4; ++k) {
      const int s = t + k * 256;  // 1024 float4 slots
      const int row = s >> 4, c4 = (s & 15) * 4;
      const float4 f = *(const float4*)&adj[(size_t)(n0 + row) * 2048 + m0 + c4];
      uint2 pk;
      pk.x = (u32)f2bf(f.x) | ((u32)f2bf(f.y) << 16);
      pk.y = (u32)f2bf(f.z) | ((u32)f2bf(f.w) << 16);
      *(uint2*)&ts[row * 136 + c4] = pk;
    }
    __syncthreads();
#pragma unroll
    for (int k = 0; k < 2; ++k) {
      const int s = t + k * 256;  // [kb 8][row 64]
      const int kb = s >> 6, row = s & 63;
      const uint4 v = *(const uint4*)&ts[row * 136 + kb * 8];
      *(uint4*)&adj_sw[(size_t)tile * 4096 + (size_t)s * 8] = v;
    }
  } else {
    const int sb = bid - 1025;  // 0..511
    const int m0g = sb * 64;
    const int w = t >> 6, l = t & 63;
    const int lg = l >> 4, lr = l & 15;
    // self-cast W image: Bs[kb 16][d 128][8] = gcn_w[kb*8+j][d]
#pragma unroll
    for (int i = 0; i < 8; ++i) {
      const int s = t + i * 256;
      const int kb = s >> 7, d = s & 127;
      u16 tmp[8];
#pragma unroll
      for (int j = 0; j < 8; ++j) tmp[j] = f2bf(gcn_w[(kb * 8 + j) * 128 + d]);
      uint4 o;
      o.x = (u32)tmp[0] | ((u32)tmp[1] << 16);
      o.y = (u32)tmp[2] | ((u32)tmp[3] << 16);
      o.z = (u32)tmp[4] | ((u32)tmp[5] << 16);
      o.w = (u32)tmp[6] | ((u32)tmp[7] << 16);
      *(uint4*)&Bs[(size_t)s * 8] = o;
    }
    // x tile 64x128 -> ts (row stride 136)
#pragma unroll
    for (int k = 0; k < 8; ++k) {
      const int s = t + k * 256;  // [row 64][c4 32]
      const int row = s >> 5, c4 = (s & 31) * 4;
      const float4 f = *(const float4*)&x[(size_t)(m0g + row) * 128 + c4];
      uint2 pk;
      pk.x = (u32)f2bf(f.x) | ((u32)f2bf(f.y) << 16);
      pk.y = (u32)f2bf(f.z) | ((u32)f2bf(f.w) << 16);
      *(uint2*)&ts[row * 136 + c4] = pk;
    }
    __syncthreads();
    f32x4 acc[8];
#pragma unroll
    for (int nf = 0; nf < 8; ++nf) {
      acc[nf][0] = 0.f; acc[nf][1] = 0.f;
      acc[nf][2] = 0.f; acc[nf][3] = 0.f;
    }
#pragma unroll
    for (int ks = 0; ks < 4; ++ks) {
      const int kb = ks * 4 + lg;
      const bf16x8 a = *(const bf16x8*)&ts[(w * 16 + lr) * 136 + kb * 8];
#pragma unroll
      for (int nf = 0; nf < 8; ++nf) {
        const bf16x8 bb = *(const bf16x8*)&Bs[((size_t)kb * 128 + nf * 16 + lr) * 8];
        acc[nf] = mfma16(a, bb, acc[nf]);
      }
    }
    __syncthreads();
    u16* os = Bs;  // transpose: os[d 128][m 64], stride 72 u16
#pragma unroll
    for (int nf = 0; nf < 8; ++nf) {
      const int d = nf * 16 + lr;
      const int mb = w * 16 + lg * 4;
      const u32 p0 = (u32)f2bf(acc[nf][0]) | ((u32)f2bf(acc[nf][1]) << 16);
      const u32 p1 = (u32)f2bf(acc[nf][2]) | ((u32)f2bf(acc[nf][3]) << 16);
      *(u32*)&os[d * 72 + mb] = p0;
      *(u32*)&os[d * 72 + mb + 2] = p1;
    }
    __syncthreads();
    const int b = m0g >> 11, mt = (m0g & 2047) >> 6;
#pragma unroll
    for (int i = 0; i < 4; ++i) {
      const int s = i * 256 + t;  // [kb 8][d 128]
      const int kb = s >> 7, d = s & 127;
      const uint4 v = *(const uint4*)&os[d * 72 + kb * 8];
      *(uint4*)&suppT_sw[((size_t)((b * 32 + mt) * 8 + kb)) * 1024 + (size_t)d * 8] = v;
    }
  }
}

// ---------------- K_gcn: 64x128 tile, BK=64, 8 waves, XCD-swizzled -----------
__global__ __launch_bounds__(512) void k_gcn(const u16* __restrict__ adj_sw,
                                             const u16* __restrict__ suppT_sw,
                                             const float* __restrict__ bias,
                                             float* __restrict__ h,
                                             float* __restrict__ psum,
                                             float* __restrict__ psq) {
  const int flat = blockIdx.y * 32 + blockIdx.x;  // 0..511
  const int nf2 = (flat & 7) * 64 + (flat >> 3);  // XCD swizzle
  const int b = nf2 >> 5, nt = nf2 & 31;
  const int n0 = nt * 64;
  const int t = threadIdx.x;
  const int w = t >> 6, l = t & 63;
  const int wm = w >> 1, wn = w & 1;
  const int lg = l >> 4, lr = l & 15;
  __shared__ __align__(16) u16 As[2][4096];
  __shared__ __align__(16) u16 Bs[2][8192];
  __shared__ float redS[4][128], redQ[4][128];

  f32x4 acc[4];
#pragma unroll
  for (int nf = 0; nf < 4; ++nf) {
    acc[nf][0] = 0.f; acc[nf][1] = 0.f;
    acc[nf][2] = 0.f; acc[nf][3] = 0.f;
  }

#define GCN_STAGE(buf, kt)                                                        \
  {                                                                               \
    gload16(adj_sw + ((size_t)(nt * 32 + (kt))) * 4096 + (size_t)t * 8,           \
            &As[buf][t * 8]);                                                     \
    _Pragma("unroll") for (int i = 0; i < 2; ++i) {                               \
      const int s = i * 512 + t;                                                  \
      gload16(suppT_sw + ((size_t)(b * 32 + (kt))) * 8192 + (size_t)s * 8,        \
              &Bs[buf][s * 8]);                                                   \
    }                                                                             \
  }

  GCN_STAGE(0, 0);
  __syncthreads();
  for (int kt = 0; kt < 32; ++kt) {
    const int cur = kt & 1;
    if (kt + 1 < 32) GCN_STAGE(cur ^ 1, kt + 1);
#pragma unroll
    for (int kb = 0; kb < 2; ++kb) {
      const int ko = kb * 4 + lg;
      const bf16x8 a0 = *(const bf16x8*)&As[cur][(ko * 64 + wm * 16 + lr) * 8];
      const bf16x8 b0 = *(const bf16x8*)&Bs[cur][(ko * 128 + wn * 64 + lr) * 8];
      const bf16x8 b1 = *(const bf16x8*)&Bs[cur][(ko * 128 + wn * 64 + 16 + lr) * 8];
      const bf16x8 b2 = *(const bf16x8*)&Bs[cur][(ko * 128 + wn * 64 + 32 + lr) * 8];
      const bf16x8 b3 = *(const bf16x8*)&Bs[cur][(ko * 128 + wn * 64 + 48 + lr) * 8];
      acc[0] = mfma16(a0, b0, acc[0]);
      acc[1] = mfma16(a0, b1, acc[1]);
      acc[2] = mfma16(a0, b2, acc[2]);
      acc[3] = mfma16(a0, b3, acc[3]);
    }
    __syncthreads();
  }
#undef GCN_STAGE
#pragma unroll
  for (int nf = 0; nf < 4; ++nf) {
    const int d = wn * 64 + nf * 16 + lr;
    const float bv = bias[d];
    float s = 0.f, q = 0.f;
#pragma unroll
    for (int r = 0; r < 4; ++r) {
      const float v = acc[nf][r] + bv;
      const int row = n0 + wm * 16 + lg * 4 + r;
      h[((size_t)(b * NN + row)) * NH + d] = v;
      s += v;
      q = fmaf(v, v, q);
    }
    s += __shfl_xor(s, 16);
    s += __shfl_xor(s, 32);
    q += __shfl_xor(q, 16);
    q += __shfl_xor(q, 32);
    if (lg == 0) {
      redS[wm][d] = s;
      redQ[wm][d] = q;
    }
  }
  __syncthreads();
  if (t < 128) {
    const int blk = b * 32 + nt;
    psum[blk * 128 + t] = redS[0][t] + redS[1][t] + redS[2][t] + redS[3][t];
    psq[blk * 128 + t] = redQ[0][t] + redQ[1][t] + redQ[2][t] + redQ[3][t];
  }
}

// ---------------- BN finalize ------------------------------------------------
__global__ __launch_bounds__(1024) void k_bnstat2(const float* __restrict__ psum,
                                                  const float* __restrict__ psq,
                                                  const float* __restrict__ gamma,
                                                  const float* __restrict__ beta,
                                                  float* __restrict__ scale,
                                                  float* __restrict__ shift) {
  const int t = threadIdx.x;
  const int d = t & 127;
  const int g = t >> 7;
  float s = 0.f, q = 0.f;
  for (int i = g; i < 512; i += 8) {
    s += psum[i * 128 + d];
    q += psq[i * 128 + d];
  }
  __shared__ float ls[8][128], lq[8][128];
  ls[g][d] = s;
  lq[g][d] = q;
  __syncthreads();
  if (t < 128) {
    s = 0.f;
    q = 0.f;
#pragma unroll
    for (int i = 0; i < 8; ++i) {
      s += ls[i][t];
      q += lq[i][t];
    }
    const float inv = 1.f / (float)(NB * NN);
    const float mean = s * inv;
    const float var = q * inv - mean * mean;
    const float sc = gamma[t] * rsqrtf(var + 1e-5f);
    scale[t] = sc;
    shift[t] = beta[t] - mean * sc;
  }
}

// ---------------- K_hp: MFMA version -----------------------------------------
__global__ __launch_bounds__(256) void k_hp(const float* __restrict__ h,
                                            const float* __restrict__ scale,
                                            const float* __restrict__ shift,
                                            const u16* __restrict__ Wg_sw,
                                            u16* __restrict__ hp_sw) {
  const int row0 = blockIdx.x * 64;
  const int t = threadIdx.x, w = t >> 6, l = t & 63;
  const int lg = l >> 4, lr = l & 15;
  __shared__ __align__(16) u16 him[8192];
  __shared__ __align__(16) u16 Wg[8192];
  __shared__ __align__(16) u16 hos[64][72];
  __shared__ float scs[128], shs[128];
#pragma unroll
  for (int i = 0; i < 4; ++i) {
    const int s0 = i * 256 + w * 64;
    gload16(Wg_sw + (size_t)(s0 + l) * 8, &Wg[(size_t)s0 * 8]);
  }
  if (t < 128) {
    scs[t] = scale[t];
    shs[t] = shift[t];
  }
  __syncthreads();
#pragma unroll
  for (int k = 0; k < 4; ++k) {
    const int s = t + k * 256;  // [row 64][kb 16]
    const int row = s >> 4, kb = s & 15;
    const float4 v0 = *(const float4*)&h[(size_t)(row0 + row) * NH + kb * 8];
    const float4 v1 = *(const float4*)&h[(size_t)(row0 + row) * NH + kb * 8 + 4];
    u16 p[8];
    p[0] = f2bf(fmaxf(fmaf(v0.x, scs[kb * 8 + 0], shs[kb * 8 + 0]), 0.f));
    p[1] = f2bf(fmaxf(fmaf(v0.y, scs[kb * 8 + 1], shs[kb * 8 + 1]), 0.f));
    p[2] = f2bf(fmaxf(fmaf(v0.z, scs[kb * 8 + 2], shs[kb * 8 + 2]), 0.f));
    p[3] = f2bf(fmaxf(fmaf(v0.w, scs[kb * 8 + 3], shs[kb * 8 + 3]), 0.f));
    p[4] = f2bf(fmaxf(fmaf(v1.x, scs[kb * 8 + 4], shs[kb * 8 + 4]), 0.f));
    p[5] = f2bf(fmaxf(fmaf(v1.y, scs[kb * 8 + 5], shs[kb * 8 + 5]), 0.f));
    p[6] = f2bf(fmaxf(fmaf(v1.z, scs[kb * 8 + 6], shs[kb * 8 + 6]), 0.f));
    p[7] = f2bf(fmaxf(fmaf(v1.w, scs[kb * 8 + 7], shs[kb * 8 + 7]), 0.f));
    uint4 o;
    o.x = (u32)p[0] | ((u32)p[1] << 16);
    o.y = (u32)p[2] | ((u32)p[3] << 16);
    o.z = (u32)p[4] | ((u32)p[5] << 16);
    o.w = (u32)p[6] | ((u32)p[7] << 16);
    const int boff = (row * 256 + kb * 16) ^ ((row & 7) << 4);
    *(uint4*)&him[boff >> 1] = o;
  }
  __syncthreads();
  f32x4 acc[4];
#pragma unroll
  for (int nf = 0; nf < 4; ++nf) {
    acc[nf][0] = 0.f; acc[nf][1] = 0.f;
    acc[nf][2] = 0.f; acc[nf][3] = 0.f;
  }
#pragma unroll
  for (int kks = 0; kks < 4; ++kks) {
    const int ko = kks * 4 + lg;
    const int arow = w * 16 + lr;
    const int aoff = (arow * 256 + ko * 16) ^ ((arow & 7) << 4);
    const bf16x8 a = *(const bf16x8*)&him[aoff >> 1];
#pragma unroll
    for (int nf = 0; nf < 4; ++nf) {
      const bf16x8 bfr = *(const bf16x8*)&Wg[(ko * 64 + nf * 16 + lr) * 8];
      acc[nf] = mfma16(a, bfr, acc[nf]);
    }
  }
#pragma unroll
  for (int nf = 0; nf < 4; ++nf) {
    const int col = nf * 16 + lr;
#pragma unroll
    for (int r = 0; r < 4; ++r) {
      hos[w * 16 + lg * 4 + r][col] = f2bf(acc[nf][r]);
    }
  }
  __syncthreads();
  const size_t tbase = (size_t)blockIdx.x * 4096;
#pragma unroll
  for (int k = 0; k < 2; ++k) {
    const int s = t + k * 256;
    const int kb = s >> 6, r6 = s & 63;
    const uint2 lo = *(const uint2*)&hos[r6][kb * 8];
    const uint2 hi = *(const uint2*)&hos[r6][kb * 8 + 4];
    uint4 o;
    o.x = lo.x; o.y = lo.y; o.z = hi.x; o.w = hi.y;
    *(uint4*)&hp_sw[tbase + kb * 512 + r6 * 8] = o;
  }
}

// ---------------- K_attnA: partial D, direct L2 fragment loads (no LDS) ------
__global__ __launch_bounds__(256) void k_attnA(const u16* __restrict__ hp_sw,
                                               float* __restrict__ Dpart) {
  const int flat = blockIdx.y * 512 + blockIdx.x;  // 0..2047
  const int lf = (flat & 7) * 256 + (flat >> 3);   // XCD swizzle
  const int b = lf >> 7;
  const int qtr = (lf & 127) >> 5;
  const int nt = lf & 31;
  const int t = threadIdx.x, w = t >> 6, l = t & 63;
  const int lg = l >> 4, lr = l & 15;
  const u16* rbase = hp_sw + (size_t)(b * 32 + nt) * 4096;
  const int qrow = (w << 4) + lr;
  const bf16x8 bq0 = *(const bf16x8*)&rbase[(lg * 64 + qrow) * 8];
  const bf16x8 bq1 = *(const bf16x8*)&rbase[((lg + 4) * 64 + qrow) * 8];
  const u16* cb = hp_sw + (size_t)(b * 32 + qtr * 8) * 4096;
  float S = 0.f;
#pragma unroll 2
  for (int mt = 0; mt < 8; ++mt) {
    const u16* base = cb + (size_t)mt * 4096;
#pragma unroll
    for (int mf = 0; mf < 4; ++mf) {
      const bf16x8 a0 = *(const bf16x8*)&base[(lg * 64 + mf * 16 + lr) * 8];
      const bf16x8 a1 = *(const bf16x8*)&base[((lg + 4) * 64 + mf * 16 + lr) * 8];
      f32x4 z;
      z[0] = 0.f; z[1] = 0.f; z[2] = 0.f; z[3] = 0.f;
      __builtin_amdgcn_s_setprio(1);
      z = mfma16(a0, bq0, z);
      z = mfma16(a1, bq1, z);
      __builtin_amdgcn_s_setprio(0);
      S += explr(z[0]) + explr(z[1]) + explr(z[2]) + explr(z[3]);
    }
  }
  S += __shfl_xor(S, 16);
  S += __shfl_xor(S, 32);
  if (l < 16) Dpart[qtr * 32768 + b * NN + nt * 64 + qrow] = S;
}

// ---------------- K_attnB: full-m S + folded scale/out (512 thr, 8 waves) ----
// waves 0-3: m 0..1023; waves 4-7: m 1024..2047. Each wave-group covers all 64 rows.
__global__ __launch_bounds__(512) void k_attnB(const u16* __restrict__ hp_sw,
                                               const float* __restrict__ Dpart,
                                               float* __restrict__ out) {
  const int flat = blockIdx.x;                // 0..511
  const int lf = (flat & 7) * 64 + (flat >> 3);  // XCD swizzle (bijective: 512%8==0)
  const int b = lf >> 5, nt = lf & 31;
  const int t = threadIdx.x, w = t >> 6, l = t & 63;
  const int lg = l >> 4, lr = l & 15;
  const int wr = w & 3;   // row-group
  const int wh = w >> 2;  // m-half
  __shared__ float iDs[2048];
  __shared__ float Sv[2][64];
  const u16* rbase = hp_sw + (size_t)(b * 32 + nt) * 4096;
  const int qrow = (wr << 4) + lr;
  const bf16x8 bq0 = *(const bf16x8*)&rbase[(lg * 64 + qrow) * 8];
  const bf16x8 bq1 = *(const bf16x8*)&rbase[((lg + 4) * 64 + qrow) * 8];
  // merge Dpart quarters -> iDs (full batch-b row range)
#pragma unroll
  for (int i = 0; i < 4; ++i) {
    const int idx = t + i * 512;
    const int n = b * NN + idx;
    iDs[idx] = 1.f / (Dpart[n] + Dpart[32768 + n] + Dpart[65536 + n] + Dpart[98304 + n]);
  }
  __syncthreads();
  const u16* cb = hp_sw + (size_t)(b * 32 + wh * 16) * 4096;
  float S = 0.f;
#pragma unroll 2
  for (int mt = 0; mt < 16; ++mt) {
    const u16* base = cb + (size_t)mt * 4096;
#pragma unroll
    for (int mf = 0; mf < 4; ++mf) {
      const bf16x8 a0 = *(const bf16x8*)&base[(lg * 64 + mf * 16 + lr) * 8];
      const bf16x8 a1 = *(const bf16x8*)&base[((lg + 4) * 64 + mf * 16 + lr) * 8];
      f32x4 z;
      z[0] = 0.f; z[1] = 0.f; z[2] = 0.f; z[3] = 0.f;
      __builtin_amdgcn_s_setprio(1);
      z = mfma16(a0, bq0, z);
      z = mfma16(a1, bq1, z);
      __builtin_amdgcn_s_setprio(0);
      const float4 dv = *(const float4*)&iDs[wh * 1024 + mt * 64 + mf * 16 + lg * 4];
      S = fmaf(explr(z[0]), dv.x, S);
      S = fmaf(explr(z[1]), dv.y, S);
      S = fmaf(explr(z[2]), dv.z, S);
      S = fmaf(explr(z[3]), dv.w, S);
    }
  }
  S += __shfl_xor(S, 16);
  S += __shfl_xor(S, 32);
  if (l < 16) Sv[wh][qrow] = S;
  __syncthreads();
  // out write: 512 threads, row = t>>3, 8 cols per thread
  const int row = t >> 3;
  const int kb = t & 7;
  const float sc = Sv[0][row] + Sv[1][row];
  const size_t R = (size_t)b * NN + nt * 64 + row;
  const uint4 v = *(const uint4*)&rbase[(kb * 64 + row) * 8];
  float4 o0, o1;
  o0.x = bf2f((u16)(v.x & 0xffff)) * sc;
  o0.y = bf2f((u16)(v.x >> 16)) * sc;
  o0.z = bf2f((u16)(v.y & 0xffff)) * sc;
  o0.w = bf2f((u16)(v.y >> 16)) * sc;
  o1.x = bf2f((u16)(v.z & 0xffff)) * sc;
  o1.y = bf2f((u16)(v.z >> 16)) * sc;
  o1.z = bf2f((u16)(v.w & 0xffff)) * sc;
  o1.w = bf2f((u16)(v.w >> 16)) * sc;
  *(float4*)&out[R * NO + kb * 8] = o0;
  *(float4*)&out[R * NO + kb * 8 + 4] = o1;
}

extern "C" void kernel_launch(void* const* d_in, const int* in_sizes, int n_in,
                              void* d_out, int out_size, void* d_ws, size_t ws_size,
                              hipStream_t stream) {
  const float* x = (const float*)d_in[0];
  // d_in[1] = adj (unused)
  const float* adj_gcn = (const float*)d_in[2];
  const float* gcn_w = (const float*)d_in[3];
  const float* gcn_b = (const float*)d_in[4];
  const float* gamma = (const float*)d_in[5];
  const float* beta = (const float*)d_in[6];
  const float* gat_w = (const float*)d_in[7];
  float* out = (float*)d_out;
  float* ws = (float*)d_ws;

  // workspace layout (float units):
  u16* adj_sw = (u16*)ws;                  // [0, 2M)
  u16* suppT_sw = (u16*)(ws + 2097152);    // [2M, 4M)
  float* hbuf = ws + 4194304;              // [4M, 8M)
  u16* hp_sw = (u16*)(ws + 8388608);       // [8M, 9M)
  float* psum = ws + 9437184;              // 65536
  float* psq = psum + 65536;               // 65536
  float* scale = psq + 65536;              // 128
  float* shift = scale + 128;              // 128
  u16* Wg_sw = (u16*)(shift + 128);        // 8192 u16 (4096 f)
  float* Dpart = ws + 9617664;             // 131072

  k_prep<<<dim3(1537), dim3(256), 0, stream>>>(x, adj_gcn, gcn_w, gat_w, suppT_sw, adj_sw, Wg_sw);
  k_gcn<<<dim3(32, 16), dim3(512), 0, stream>>>(adj_sw, suppT_sw, gcn_b, hbuf, psum, psq);
  k_bnstat2<<<dim3(1), dim3(1024), 0, stream>>>(psum, psq, gamma, beta, scale, shift);
  k_hp<<<dim3(512), dim3(256), 0, stream>>>(hbuf, scale, shift, Wg_sw, hp_sw);
  k_attnA<<<dim3(512, 4), dim3(256), 0, stream>>>(hp_sw, Dpart);
  k_attnB<<<dim3(512), dim3(512), 0, stream>>>(hp_sw, Dpart, out);
}

// Round 15
// 100.697 us; speedup vs baseline: 3.9122x; 1.0646x over previous
//
#include <hip/hip_runtime.h>
#include <math.h>

#define NB 16
#define NN 2048
#define NF 128
#define NH 128
#define NO 64

typedef short bf16x8 __attribute__((ext_vector_type(8)));
typedef float f32x4 __attribute__((ext_vector_type(4)));
typedef unsigned short u16;
typedef unsigned int u32;

#define LOG2E 1.4426950408889634f
#define EXPSHIFT 43.28085122666891f  // 30 * log2(e)

__device__ __forceinline__ u16 f2bf(float f) {
  u32 u = __builtin_bit_cast(u32, f);
  return (u16)((u + 0x7fffu + ((u >> 16) & 1u)) >> 16);
}
__device__ __forceinline__ float bf2f(u16 h) {
  u32 u = ((u32)h) << 16;
  return __builtin_bit_cast(float, u);
}

__device__ __forceinline__ void gload16(const void* g, void* l) {
  __builtin_amdgcn_global_load_lds((const __attribute__((address_space(1))) void*)g,
                                   (__attribute__((address_space(3))) void*)l, 16, 0, 0);
}
__device__ __forceinline__ f32x4 mfma16(bf16x8 a, bf16x8 b, f32x4 c) {
  return __builtin_amdgcn_mfma_f32_16x16x32_bf16(a, b, c, 0, 0, 0);
}
// exp(lrelu(z) - 30): max, mul, fma, v_exp
__device__ __forceinline__ float explr(float z) {
  return __builtin_amdgcn_exp2f(fmaf(fmaxf(z, 0.2f * z), LOG2E, -EXPSHIFT));
}

// ---------------- K_prep: Wg + adj swizzle + support GEMM, one launch --------
__global__ __launch_bounds__(256) void k_prep(const float* __restrict__ x,
                                              const float* __restrict__ adj,
                                              const float* __restrict__ gcn_w,
                                              const float* __restrict__ gat_w,
                                              u16* __restrict__ suppT_sw,
                                              u16* __restrict__ adj_sw,
                                              u16* __restrict__ Wg_sw) {
  __shared__ __align__(16) u16 ts[64 * 136];  // 17.4KB
  __shared__ __align__(16) u16 Bs[16384];     // 32KB W image; reused as os
  const int t = threadIdx.x;
  const int bid = blockIdx.x;
  if (bid == 0) {
#pragma unroll
    for (int it = 0; it < 4; ++it) {
      const int s = t + it * 256;  // [kb 16][col 64]
      const int kb = s >> 6, col = s & 63;
      u16 tmp[8];
#pragma unroll
      for (int j = 0; j < 8; ++j) tmp[j] = f2bf(gat_w[(kb * 8 + j) * 64 + col]);
      uint4 o;
      o.x = (u32)tmp[0] | ((u32)tmp[1] << 16);
      o.y = (u32)tmp[2] | ((u32)tmp[3] << 16);
      o.z = (u32)tmp[4] | ((u32)tmp[5] << 16);
      o.w = (u32)tmp[6] | ((u32)tmp[7] << 16);
      *(uint4*)&Wg_sw[(size_t)s * 8] = o;
    }
  } else if (bid < 1025) {
    const int tile = bid - 1;  // [nt 32][kt 32]
    const int n0 = (tile >> 5) * 64, m0 = (tile & 31) * 64;
#pragma unroll
    for (int k = 0; k < 4; ++k) {
      const int s = t + k * 256;  // 1024 float4 slots
      const int row = s >> 4, c4 = (s & 15) * 4;
      const float4 f = *(const float4*)&adj[(size_t)(n0 + row) * 2048 + m0 + c4];
      uint2 pk;
      pk.x = (u32)f2bf(f.x) | ((u32)f2bf(f.y) << 16);
      pk.y = (u32)f2bf(f.z) | ((u32)f2bf(f.w) << 16);
      *(uint2*)&ts[row * 136 + c4] = pk;
    }
    __syncthreads();
#pragma unroll
    for (int k = 0; k < 2; ++k) {
      const int s = t + k * 256;  // [kb 8][row 64]
      const int kb = s >> 6, row = s & 63;
      const uint4 v = *(const uint4*)&ts[row * 136 + kb * 8];
      *(uint4*)&adj_sw[(size_t)tile * 4096 + (size_t)s * 8] = v;
    }
  } else {
    const int sb = bid - 1025;  // 0..511
    const int m0g = sb * 64;
    const int w = t >> 6, l = t & 63;
    const int lg = l >> 4, lr = l & 15;
    // self-cast W image: Bs[kb 16][d 128][8] = gcn_w[kb*8+j][d]
#pragma unroll
    for (int i = 0; i < 8; ++i) {
      const int s = t + i * 256;
      const int kb = s >> 7, d = s & 127;
      u16 tmp[8];
#pragma unroll
      for (int j = 0; j < 8; ++j) tmp[j] = f2bf(gcn_w[(kb * 8 + j) * 128 + d]);
      uint4 o;
      o.x = (u32)tmp[0] | ((u32)tmp[1] << 16);
      o.y = (u32)tmp[2] | ((u32)tmp[3] << 16);
      o.z = (u32)tmp[4] | ((u32)tmp[5] << 16);
      o.w = (u32)tmp[6] | ((u32)tmp[7] << 16);
      *(uint4*)&Bs[(size_t)s * 8] = o;
    }
    // x tile 64x128 -> ts (row stride 136)
#pragma unroll
    for (int k = 0; k < 8; ++k) {
      const int s = t + k * 256;  // [row 64][c4 32]
      const int row = s >> 5, c4 = (s & 31) * 4;
      const float4 f = *(const float4*)&x[(size_t)(m0g + row) * 128 + c4];
      uint2 pk;
      pk.x = (u32)f2bf(f.x) | ((u32)f2bf(f.y) << 16);
      pk.y = (u32)f2bf(f.z) | ((u32)f2bf(f.w) << 16);
      *(uint2*)&ts[row * 136 + c4] = pk;
    }
    __syncthreads();
    f32x4 acc[8];
#pragma unroll
    for (int nf = 0; nf < 8; ++nf) {
      acc[nf][0] = 0.f; acc[nf][1] = 0.f;
      acc[nf][2] = 0.f; acc[nf][3] = 0.f;
    }
#pragma unroll
    for (int ks = 0; ks < 4; ++ks) {
      const int kb = ks * 4 + lg;
      const bf16x8 a = *(const bf16x8*)&ts[(w * 16 + lr) * 136 + kb * 8];
#pragma unroll
      for (int nf = 0; nf < 8; ++nf) {
        const bf16x8 bb = *(const bf16x8*)&Bs[((size_t)kb * 128 + nf * 16 + lr) * 8];
        acc[nf] = mfma16(a, bb, acc[nf]);
      }
    }
    __syncthreads();
    u16* os = Bs;  // transpose: os[d 128][m 64], stride 72 u16
#pragma unroll
    for (int nf = 0; nf < 8; ++nf) {
      const int d = nf * 16 + lr;
      const int mb = w * 16 + lg * 4;
      const u32 p0 = (u32)f2bf(acc[nf][0]) | ((u32)f2bf(acc[nf][1]) << 16);
      const u32 p1 = (u32)f2bf(acc[nf][2]) | ((u32)f2bf(acc[nf][3]) << 16);
      *(u32*)&os[d * 72 + mb] = p0;
      *(u32*)&os[d * 72 + mb + 2] = p1;
    }
    __syncthreads();
    const int b = m0g >> 11, mt = (m0g & 2047) >> 6;
#pragma unroll
    for (int i = 0; i < 4; ++i) {
      const int s = i * 256 + t;  // [kb 8][d 128]
      const int kb = s >> 7, d = s & 127;
      const uint4 v = *(const uint4*)&os[d * 72 + kb * 8];
      *(uint4*)&suppT_sw[((size_t)((b * 32 + mt) * 8 + kb)) * 1024 + (size_t)d * 8] = v;
    }
  }
}

// ---------------- K_gcn: 128x128 tile, BK=64, 8 waves (4m x 2n), XCD-swz -----
// A-tile = two adjacent 64-row adj_sw tiles; As layout [half 2][kb 8][row 64][8].
__global__ __launch_bounds__(512) void k_gcn(const u16* __restrict__ adj_sw,
                                             const u16* __restrict__ suppT_sw,
                                             const float* __restrict__ bias,
                                             float* __restrict__ h,
                                             float* __restrict__ psum,
                                             float* __restrict__ psq) {
  const int flat = blockIdx.x;                   // 0..255
  const int lf = (flat & 7) * 32 + (flat >> 3);  // XCD swizzle (256%8==0)
  const int b = lf >> 4, ntp = lf & 15;          // 128-row tile index
  const int t = threadIdx.x;
  const int w = t >> 6, l = t & 63;
  const int wm = w >> 1, wn = w & 1;  // wm 0..3 (32-row group), wn 0..1 (64-col)
  const int lg = l >> 4, lr = l & 15;
  __shared__ __align__(16) u16 As[2][8192];  // [half 2][kb 8][row 64][8]
  __shared__ __align__(16) u16 Bs[2][8192];  // [kb 8][d 128][8]
  __shared__ float redS[4][128], redQ[4][128];

  f32x4 acc[2][4];
#pragma unroll
  for (int mf = 0; mf < 2; ++mf)
#pragma unroll
    for (int nf = 0; nf < 4; ++nf) {
      acc[mf][nf][0] = 0.f; acc[mf][nf][1] = 0.f;
      acc[mf][nf][2] = 0.f; acc[mf][nf][3] = 0.f;
    }

#define GCN_STAGE(buf, kt)                                                          \
  {                                                                                 \
    _Pragma("unroll") for (int i = 0; i < 2; ++i) {                                 \
      const int s = i * 512 + t;  /* [half][kb8][row64] */                          \
      const int half = s >> 9, inner = s & 511;                                     \
      gload16(adj_sw + ((size_t)((ntp * 2 + half) * 32 + (kt))) * 4096 +            \
                  (size_t)inner * 8,                                                \
              &As[buf][s * 8]);                                                     \
    }                                                                               \
    _Pragma("unroll") for (int i = 0; i < 2; ++i) {                                 \
      const int s = i * 512 + t;                                                    \
      gload16(suppT_sw + ((size_t)(b * 32 + (kt))) * 8192 + (size_t)s * 8,          \
              &Bs[buf][s * 8]);                                                     \
    }                                                                               \
  }

  GCN_STAGE(0, 0);
  __syncthreads();
  const int half = wm >> 1;
  for (int kt = 0; kt < 32; ++kt) {
    const int cur = kt & 1;
    if (kt + 1 < 32) GCN_STAGE(cur ^ 1, kt + 1);
#pragma unroll
    for (int kb = 0; kb < 2; ++kb) {
      const int ko = kb * 4 + lg;
      const int r0 = (wm & 1) * 32 + lr;
      const bf16x8 a0 = *(const bf16x8*)&As[cur][half * 4096 + (ko * 64 + r0) * 8];
      const bf16x8 a1 = *(const bf16x8*)&As[cur][half * 4096 + (ko * 64 + r0 + 16) * 8];
      const bf16x8 b0 = *(const bf16x8*)&Bs[cur][(ko * 128 + wn * 64 + lr) * 8];
      const bf16x8 b1 = *(const bf16x8*)&Bs[cur][(ko * 128 + wn * 64 + 16 + lr) * 8];
      const bf16x8 b2 = *(const bf16x8*)&Bs[cur][(ko * 128 + wn * 64 + 32 + lr) * 8];
      const bf16x8 b3 = *(const bf16x8*)&Bs[cur][(ko * 128 + wn * 64 + 48 + lr) * 8];
      acc[0][0] = mfma16(a0, b0, acc[0][0]);
      acc[0][1] = mfma16(a0, b1, acc[0][1]);
      acc[0][2] = mfma16(a0, b2, acc[0][2]);
      acc[0][3] = mfma16(a0, b3, acc[0][3]);
      acc[1][0] = mfma16(a1, b0, acc[1][0]);
      acc[1][1] = mfma16(a1, b1, acc[1][1]);
      acc[1][2] = mfma16(a1, b2, acc[1][2]);
      acc[1][3] = mfma16(a1, b3, acc[1][3]);
    }
    __syncthreads();
  }
#undef GCN_STAGE
  // epilogue: bias + h write + BN partials (128 rows per block)
  const int n0 = ntp * 128;
#pragma unroll
  for (int nf = 0; nf < 4; ++nf) {
    const int d = wn * 64 + nf * 16 + lr;
    const float bv = bias[d];
    float s = 0.f, q = 0.f;
#pragma unroll
    for (int mf = 0; mf < 2; ++mf) {
#pragma unroll
      for (int r = 0; r < 4; ++r) {
        const float v = acc[mf][nf][r] + bv;
        const int row = n0 + wm * 32 + mf * 16 + lg * 4 + r;
        h[((size_t)(b * NN + row)) * NH + d] = v;
        s += v;
        q = fmaf(v, v, q);
      }
    }
    s += __shfl_xor(s, 16);
    s += __shfl_xor(s, 32);
    q += __shfl_xor(q, 16);
    q += __shfl_xor(q, 32);
    if (lg == 0) {
      redS[wm][d] = s;
      redQ[wm][d] = q;
    }
  }
  __syncthreads();
  if (t < 128) {
    const int blk = b * 16 + ntp;
    psum[blk * 128 + t] = redS[0][t] + redS[1][t] + redS[2][t] + redS[3][t];
    psq[blk * 128 + t] = redQ[0][t] + redQ[1][t] + redQ[2][t] + redQ[3][t];
  }
}

// ---------------- BN finalize (256 partials) ---------------------------------
__global__ __launch_bounds__(1024) void k_bnstat2(const float* __restrict__ psum,
                                                  const float* __restrict__ psq,
                                                  const float* __restrict__ gamma,
                                                  const float* __restrict__ beta,
                                                  float* __restrict__ scale,
                                                  float* __restrict__ shift) {
  const int t = threadIdx.x;
  const int d = t & 127;
  const int g = t >> 7;
  float s = 0.f, q = 0.f;
  for (int i = g; i < 256; i += 8) {
    s += psum[i * 128 + d];
    q += psq[i * 128 + d];
  }
  __shared__ float ls[8][128], lq[8][128];
  ls[g][d] = s;
  lq[g][d] = q;
  __syncthreads();
  if (t < 128) {
    s = 0.f;
    q = 0.f;
#pragma unroll
    for (int i = 0; i < 8; ++i) {
      s += ls[i][t];
      q += lq[i][t];
    }
    const float inv = 1.f / (float)(NB * NN);
    const float mean = s * inv;
    const float var = q * inv - mean * mean;
    const float sc = gamma[t] * rsqrtf(var + 1e-5f);
    scale[t] = sc;
    shift[t] = beta[t] - mean * sc;
  }
}

// ---------------- K_hp: MFMA version -----------------------------------------
__global__ __launch_bounds__(256) void k_hp(const float* __restrict__ h,
                                            const float* __restrict__ scale,
                                            const float* __restrict__ shift,
                                            const u16* __restrict__ Wg_sw,
                                            u16* __restrict__ hp_sw) {
  const int row0 = blockIdx.x * 64;
  const int t = threadIdx.x, w = t >> 6, l = t & 63;
  const int lg = l >> 4, lr = l & 15;
  __shared__ __align__(16) u16 him[8192];
  __shared__ __align__(16) u16 Wg[8192];
  __shared__ __align__(16) u16 hos[64][72];
  __shared__ float scs[128], shs[128];
#pragma unroll
  for (int i = 0; i < 4; ++i) {
    const int s0 = i * 256 + w * 64;
    gload16(Wg_sw + (size_t)(s0 + l) * 8, &Wg[(size_t)s0 * 8]);
  }
  if (t < 128) {
    scs[t] = scale[t];
    shs[t] = shift[t];
  }
  __syncthreads();
#pragma unroll
  for (int k = 0; k < 4; ++k) {
    const int s = t + k * 256;  // [row 64][kb 16]
    const int row = s >> 4, kb = s & 15;
    const float4 v0 = *(const float4*)&h[(size_t)(row0 + row) * NH + kb * 8];
    const float4 v1 = *(const float4*)&h[(size_t)(row0 + row) * NH + kb * 8 + 4];
    u16 p[8];
    p[0] = f2bf(fmaxf(fmaf(v0.x, scs[kb * 8 + 0], shs[kb * 8 + 0]), 0.f));
    p[1] = f2bf(fmaxf(fmaf(v0.y, scs[kb * 8 + 1], shs[kb * 8 + 1]), 0.f));
    p[2] = f2bf(fmaxf(fmaf(v0.z, scs[kb * 8 + 2], shs[kb * 8 + 2]), 0.f));
    p[3] = f2bf(fmaxf(fmaf(v0.w, scs[kb * 8 + 3], shs[kb * 8 + 3]), 0.f));
    p[4] = f2bf(fmaxf(fmaf(v1.x, scs[kb * 8 + 4], shs[kb * 8 + 4]), 0.f));
    p[5] = f2bf(fmaxf(fmaf(v1.y, scs[kb * 8 + 5], shs[kb * 8 + 5]), 0.f));
    p[6] = f2bf(fmaxf(fmaf(v1.z, scs[kb * 8 + 6], shs[kb * 8 + 6]), 0.f));
    p[7] = f2bf(fmaxf(fmaf(v1.w, scs[kb * 8 + 7], shs[kb * 8 + 7]), 0.f));
    uint4 o;
    o.x = (u32)p[0] | ((u32)p[1] << 16);
    o.y = (u32)p[2] | ((u32)p[3] << 16);
    o.z = (u32)p[4] | ((u32)p[5] << 16);
    o.w = (u32)p[6] | ((u32)p[7] << 16);
    const int boff = (row * 256 + kb * 16) ^ ((row & 7) << 4);
    *(uint4*)&him[boff >> 1] = o;
  }
  __syncthreads();
  f32x4 acc[4];
#pragma unroll
  for (int nf = 0; nf < 4; ++nf) {
    acc[nf][0] = 0.f; acc[nf][1] = 0.f;
    acc[nf][2] = 0.f; acc[nf][3] = 0.f;
  }
#pragma unroll
  for (int kks = 0; kks < 4; ++kks) {
    const int ko = kks * 4 + lg;
    const int arow = w * 16 + lr;
    const int aoff = (arow * 256 + ko * 16) ^ ((arow & 7) << 4);
    const bf16x8 a = *(const bf16x8*)&him[aoff >> 1];
#pragma unroll
    for (int nf = 0; nf < 4; ++nf) {
      const bf16x8 bfr = *(const bf16x8*)&Wg[(ko * 64 + nf * 16 + lr) * 8];
      acc[nf] = mfma16(a, bfr, acc[nf]);
    }
  }
#pragma unroll
  for (int nf = 0; nf < 4; ++nf) {
    const int col = nf * 16 + lr;
#pragma unroll
    for (int r = 0; r < 4; ++r) {
      hos[w * 16 + lg * 4 + r][col] = f2bf(acc[nf][r]);
    }
  }
  __syncthreads();
  const size_t tbase = (size_t)blockIdx.x * 4096;
#pragma unroll
  for (int k = 0; k < 2; ++k) {
    const int s = t + k * 256;
    const int kb = s >> 6, r6 = s & 63;
    const uint2 lo = *(const uint2*)&hos[r6][kb * 8];
    const uint2 hi = *(const uint2*)&hos[r6][kb * 8 + 4];
    uint4 o;
    o.x = lo.x; o.y = lo.y; o.z = hi.x; o.w = hi.y;
    *(uint4*)&hp_sw[tbase + kb * 512 + r6 * 8] = o;
  }
}

// ---------------- K_attnA: partial D, direct L2 fragment loads (no LDS) ------
__global__ __launch_bounds__(256) void k_attnA(const u16* __restrict__ hp_sw,
                                               float* __restrict__ Dpart) {
  const int flat = blockIdx.y * 512 + blockIdx.x;  // 0..2047
  const int lf = (flat & 7) * 256 + (flat >> 3);   // XCD swizzle
  const int b = lf >> 7;
  const int qtr = (lf & 127) >> 5;
  const int nt = lf & 31;
  const int t = threadIdx.x, w = t >> 6, l = t & 63;
  const int lg = l >> 4, lr = l & 15;
  const u16* rbase = hp_sw + (size_t)(b * 32 + nt) * 4096;
  const int qrow = (w << 4) + lr;
  const bf16x8 bq0 = *(const bf16x8*)&rbase[(lg * 64 + qrow) * 8];
  const bf16x8 bq1 = *(const bf16x8*)&rbase[((lg + 4) * 64 + qrow) * 8];
  const u16* cb = hp_sw + (size_t)(b * 32 + qtr * 8) * 4096;
  float S = 0.f;
#pragma unroll 2
  for (int mt = 0; mt < 8; ++mt) {
    const u16* base = cb + (size_t)mt * 4096;
#pragma unroll
    for (int mf = 0; mf < 4; ++mf) {
      const bf16x8 a0 = *(const bf16x8*)&base[(lg * 64 + mf * 16 + lr) * 8];
      const bf16x8 a1 = *(const bf16x8*)&base[((lg + 4) * 64 + mf * 16 + lr) * 8];
      f32x4 z;
      z[0] = 0.f; z[1] = 0.f; z[2] = 0.f; z[3] = 0.f;
      __builtin_amdgcn_s_setprio(1);
      z = mfma16(a0, bq0, z);
      z = mfma16(a1, bq1, z);
      __builtin_amdgcn_s_setprio(0);
      S += explr(z[0]) + explr(z[1]) + explr(z[2]) + explr(z[3]);
    }
  }
  S += __shfl_xor(S, 16);
  S += __shfl_xor(S, 32);
  if (l < 16) Dpart[qtr * 32768 + b * NN + nt * 64 + qrow] = S;
}

// ---------------- K_attnB: full-m S + folded scale/out (512 thr, 8 waves) ----
__global__ __launch_bounds__(512) void k_attnB(const u16* __restrict__ hp_sw,
                                               const float* __restrict__ Dpart,
                                               float* __restrict__ out) {
  const int flat = blockIdx.x;                   // 0..511
  const int lf = (flat & 7) * 64 + (flat >> 3);  // XCD swizzle
  const int b = lf >> 5, nt = lf & 31;
  const int t = threadIdx.x, w = t >> 6, l = t & 63;
  const int lg = l >> 4, lr = l & 15;
  const int wr = w & 3;   // row-group
  const int wh = w >> 2;  // m-half
  __shared__ float iDs[2048];
  __shared__ float Sv[2][64];
  const u16* rbase = hp_sw + (size_t)(b * 32 + nt) * 4096;
  const int qrow = (wr << 4) + lr;
  const bf16x8 bq0 = *(const bf16x8*)&rbase[(lg * 64 + qrow) * 8];
  const bf16x8 bq1 = *(const bf16x8*)&rbase[((lg + 4) * 64 + qrow) * 8];
#pragma unroll
  for (int i = 0; i < 4; ++i) {
    const int idx = t + i * 512;
    const int n = b * NN + idx;
    iDs[idx] = 1.f / (Dpart[n] + Dpart[32768 + n] + Dpart[65536 + n] + Dpart[98304 + n]);
  }
  __syncthreads();
  const u16* cb = hp_sw + (size_t)(b * 32 + wh * 16) * 4096;
  float S = 0.f;
#pragma unroll 2
  for (int mt = 0; mt < 16; ++mt) {
    const u16* base = cb + (size_t)mt * 4096;
#pragma unroll
    for (int mf = 0; mf < 4; ++mf) {
      const bf16x8 a0 = *(const bf16x8*)&base[(lg * 64 + mf * 16 + lr) * 8];
      const bf16x8 a1 = *(const bf16x8*)&base[((lg + 4) * 64 + mf * 16 + lr) * 8];
      f32x4 z;
      z[0] = 0.f; z[1] = 0.f; z[2] = 0.f; z[3] = 0.f;
      __builtin_amdgcn_s_setprio(1);
      z = mfma16(a0, bq0, z);
      z = mfma16(a1, bq1, z);
      __builtin_amdgcn_s_setprio(0);
      const float4 dv = *(const float4*)&iDs[wh * 1024 + mt * 64 + mf * 16 + lg * 4];
      S = fmaf(explr(z[0]), dv.x, S);
      S = fmaf(explr(z[1]), dv.y, S);
      S = fmaf(explr(z[2]), dv.z, S);
      S = fmaf(explr(z[3]), dv.w, S);
    }
  }
  S += __shfl_xor(S, 16);
  S += __shfl_xor(S, 32);
  if (l < 16) Sv[wh][qrow] = S;
  __syncthreads();
  const int row = t >> 3;
  const int kb = t & 7;
  const float sc = Sv[0][row] + Sv[1][row];
  const size_t R = (size_t)b * NN + nt * 64 + row;
  const uint4 v = *(const uint4*)&rbase[(kb * 64 + row) * 8];
  float4 o0, o1;
  o0.x = bf2f((u16)(v.x & 0xffff)) * sc;
  o0.y = bf2f((u16)(v.x >> 16)) * sc;
  o0.z = bf2f((u16)(v.y & 0xffff)) * sc;
  o0.w = bf2f((u16)(v.y >> 16)) * sc;
  o1.x = bf2f((u16)(v.z & 0xffff)) * sc;
  o1.y = bf2f((u16)(v.z >> 16)) * sc;
  o1.z = bf2f((u16)(v.w & 0xffff)) * sc;
  o1.w = bf2f((u16)(v.w >> 16)) * sc;
  *(float4*)&out[R * NO + kb * 8] = o0;
  *(float4*)&out[R * NO + kb * 8 + 4] = o1;
}

extern "C" void kernel_launch(void* const* d_in, const int* in_sizes, int n_in,
                              void* d_out, int out_size, void* d_ws, size_t ws_size,
                              hipStream_t stream) {
  const float* x = (const float*)d_in[0];
  // d_in[1] = adj (unused)
  const float* adj_gcn = (const float*)d_in[2];
  const float* gcn_w = (const float*)d_in[3];
  const float* gcn_b = (const float*)d_in[4];
  const float* gamma = (const float*)d_in[5];
  const float* beta = (const float*)d_in[6];
  const float* gat_w = (const float*)d_in[7];
  float* out = (float*)d_out;
  float* ws = (float*)d_ws;

  // workspace layout (float units):
  u16* adj_sw = (u16*)ws;                  // [0, 2M)
  u16* suppT_sw = (u16*)(ws + 2097152);    // [2M, 4M)
  float* hbuf = ws + 4194304;              // [4M, 8M)
  u16* hp_sw = (u16*)(ws + 8388608);       // [8M, 9M)
  float* psum = ws + 9437184;              // 32768 (256x128)
  float* psq = psum + 32768;               // 32768
  float* scale = psq + 32768;              // 128
  float* shift = scale + 128;              // 128
  u16* Wg_sw = (u16*)(shift + 128);        // 8192 u16 (4096 f)
  float* Dpart = ws + 9617664;             // 131072

  k_prep<<<dim3(1537), dim3(256), 0, stream>>>(x, adj_gcn, gcn_w, gat_w, suppT_sw, adj_sw, Wg_sw);
  k_gcn<<<dim3(256), dim3(512), 0, stream>>>(adj_sw, suppT_sw, gcn_b, hbuf, psum, psq);
  k_bnstat2<<<dim3(1), dim3(1024), 0, stream>>>(psum, psq, gamma, beta, scale, shift);
  k_hp<<<dim3(512), dim3(256), 0, stream>>>(hbuf, scale, shift, Wg_sw, hp_sw);
  k_attnA<<<dim3(512, 4), dim3(256), 0, stream>>>(hp_sw, Dpart);
  k_attnB<<<dim3(512), dim3(512), 0, stream>>>(hp_sw, Dpart, out);
}